// Round 1
// baseline (957.843 us; speedup 1.0000x reference)
//
#include <hip/hip_runtime.h>

#define TT 128

// LIF constants
#define DECAY_U 0.75f
#define DECAY_V 0.96875f
#define THETA   5120.0f
#define POOLW   88.0f

// ---------------- Layer 1: sum_pool(x,4)*88, no delay ----------------
// x: [8,2,128,128,128] -> d1: [8,2,32,32,128]
__global__ void pool1_k(const float* __restrict__ x, float* __restrict__ d1) {
    int id = blockIdx.x * blockDim.x + threadIdx.x;
    if (id >= 8*2*32*32*128) return;
    int t = id & 127;
    int n = id >> 7;
    int px = n & 31, py = (n >> 5) & 31, c = (n >> 10) & 1, b = n >> 11;
    const float* base = x + (size_t)((((b*2 + c)*128 + py*4)*128) + px*4) * 128 + t;
    float s = 0.f;
    #pragma unroll
    for (int dy = 0; dy < 4; ++dy)
        #pragma unroll
        for (int dx = 0; dx < 4; ++dx)
            s += base[(dy*128 + dx) * 128];
    d1[id] = s * POOLW;
}

// ---------------- Generic LIF, in place: drive -> spikes ----------------
__global__ void lif_k(float* __restrict__ buf, int N) {
    int n = blockIdx.x * blockDim.x + threadIdx.x;
    if (n >= N) return;
    float* p = buf + (size_t)n * TT;
    float u = 0.f, v = 0.f;
    int refc = 0;
    for (int t = 0; t < TT; ++t) {
        float xt = p[t];
        // u = u*DECAY_U + xt*64  (separate roundings, no FMA)
        u = __fadd_rn(__fmul_rn(u, DECAY_U), __fmul_rn(xt, 64.0f));
        float vn = __fadd_rn(__fmul_rn(v, DECAY_V), u);
        v = refc ? 0.0f : vn;
        float s = (v >= THETA) ? 1.0f : 0.0f;
        if (s > 0.f) { refc = 1; v = 0.f; }
        else         { refc = refc > 0 ? refc - 1 : 0; }
        p[t] = s;
    }
}

// ---------------- Layer 2: conv1 5x5 SAME, 2->16, input delayed ----------------
// s1: [8,2,32,32,128] -> d2: [8,16,32,32,128]
__global__ void conv1_k(const float* __restrict__ s1, const float* __restrict__ w1,
                        float* __restrict__ d2) {
    int id = blockIdx.x * blockDim.x + threadIdx.x;
    if (id >= 8*16*32*32*128) return;
    int t = id & 127;
    int n = id >> 7;
    int px = n & 31, py = (n >> 5) & 31, oc = (n >> 10) & 15, b = n >> 14;
    float acc = 0.f;
    if (t > 0) {
        const float* sp = s1 + (t - 1);
        #pragma unroll
        for (int c = 0; c < 2; ++c) {
            const float* wp = w1 + (oc*2 + c) * 25;
            const float* ip = sp + (size_t)((b*2 + c) * 32) * 32 * 128;
            #pragma unroll
            for (int ky = 0; ky < 5; ++ky) {
                int iy = py + ky - 2;
                if (iy < 0 || iy >= 32) continue;
                #pragma unroll
                for (int kx = 0; kx < 5; ++kx) {
                    int ix = px + kx - 2;
                    if (ix < 0 || ix >= 32) continue;
                    acc = fmaf(wp[ky*5 + kx], ip[(iy*32 + ix) * 128], acc);
                }
            }
        }
    }
    d2[id] = acc;
}

// ---------------- Layer 3: sum_pool(s2,2)*88, delayed ----------------
// s2: [8,16,32,32,128] -> d3: [8,16,16,16,128]
__global__ void pool2_k(const float* __restrict__ s2, float* __restrict__ d3) {
    int id = blockIdx.x * blockDim.x + threadIdx.x;
    if (id >= 8*16*16*16*128) return;
    int t = id & 127;
    int n = id >> 7;
    int px = n & 15, py = (n >> 4) & 15, c = (n >> 8) & 15, b = n >> 12;
    float acc = 0.f;
    if (t > 0) {
        const float* ip = s2 + (size_t)(((b*16 + c)*32 + py*2)*32 + px*2) * 128 + (t - 1);
        acc = (ip[0] + ip[128] + ip[32*128] + ip[33*128]) * POOLW;
    }
    d3[id] = acc;
}

// ---------------- Layer 4: conv2 3x3 SAME, 16->32, delayed ----------------
// s3: [8,16,16,16,128] -> d4: [8,32,16,16,128]
__global__ void conv2_k(const float* __restrict__ s3, const float* __restrict__ w2,
                        float* __restrict__ d4) {
    int id = blockIdx.x * blockDim.x + threadIdx.x;
    if (id >= 8*32*16*16*128) return;
    int t = id & 127;
    int n = id >> 7;
    int px = n & 15, py = (n >> 4) & 15, oc = (n >> 8) & 31, b = n >> 13;
    float acc = 0.f;
    if (t > 0) {
        const float* sp = s3 + (t - 1);
        for (int c = 0; c < 16; ++c) {
            const float* wp = w2 + (oc*16 + c) * 9;
            const float* ip = sp + (size_t)((b*16 + c) * 16) * 16 * 128;
            #pragma unroll
            for (int ky = 0; ky < 3; ++ky) {
                int iy = py + ky - 1;
                if (iy < 0 || iy >= 16) continue;
                #pragma unroll
                for (int kx = 0; kx < 3; ++kx) {
                    int ix = px + kx - 1;
                    if (ix < 0 || ix >= 16) continue;
                    acc = fmaf(wp[ky*3 + kx], ip[(iy*16 + ix) * 128], acc);
                }
            }
        }
    }
    d4[id] = acc;
}

// ---------------- Layer 5: sum_pool(s4,2)*88, delayed ----------------
// s4: [8,32,16,16,128] -> d5: [8,32,8,8,128]
__global__ void pool3_k(const float* __restrict__ s4, float* __restrict__ d5) {
    int id = blockIdx.x * blockDim.x + threadIdx.x;
    if (id >= 8*32*8*8*128) return;
    int t = id & 127;
    int n = id >> 7;
    int px = n & 7, py = (n >> 3) & 7, c = (n >> 6) & 31, b = n >> 11;
    float acc = 0.f;
    if (t > 0) {
        const float* ip = s4 + (size_t)(((b*32 + c)*16 + py*2)*16 + px*2) * 128 + (t - 1);
        acc = (ip[0] + ip[128] + ip[16*128] + ip[17*128]) * POOLW;
    }
    d5[id] = acc;
}

// ---------------- Layer 6: fc1 2048->512, delayed ----------------
// s5: [8,2048,128] -> d6: [8,512,128]; 8 outputs per thread (og + k*64)
__global__ void fc1_k(const float* __restrict__ s5, const float* __restrict__ wf1,
                      float* __restrict__ d6) {
    int id = blockIdx.x * blockDim.x + threadIdx.x;
    if (id >= 8*64*128) return;
    int t = id & 127;
    int n = id >> 7;
    int og = n & 63, b = n >> 6;
    float acc[8] = {0.f, 0.f, 0.f, 0.f, 0.f, 0.f, 0.f, 0.f};
    if (t > 0) {
        const float* sp = s5 + (size_t)b * 2048 * 128 + (t - 1);
        #pragma unroll 4
        for (int f = 0; f < 2048; ++f) {
            float sv = sp[(size_t)f * 128];
            #pragma unroll
            for (int k = 0; k < 8; ++k)
                acc[k] = fmaf(wf1[(size_t)(og + k*64) * 2048 + f], sv, acc[k]);
        }
    }
    #pragma unroll
    for (int k = 0; k < 8; ++k)
        d6[((size_t)(b*512 + og + k*64)) * 128 + t] = acc[k];
}

// ---------------- Layer 7 drive: fc2 512->11, delayed ----------------
// s6: [8,512,128] -> d7: [8,11,128]
__global__ void fc2_k(const float* __restrict__ s6, const float* __restrict__ wf2,
                      float* __restrict__ d7) {
    int id = blockIdx.x * blockDim.x + threadIdx.x;
    if (id >= 8*11*128) return;
    int t = id & 127;
    int n = id >> 7;
    int o = n % 11, b = n / 11;
    float acc = 0.f;
    if (t > 0) {
        const float* sp = s6 + (size_t)b * 512 * 128 + (t - 1);
        const float* wp = wf2 + o * 512;
        #pragma unroll 4
        for (int f = 0; f < 512; ++f)
            acc = fmaf(wp[f], sp[(size_t)f * 128], acc);
    }
    d7[id] = acc;
}

// ---------------- Layer 7 LIF + final delay_shift, writes d_out ----------------
__global__ void lif_out_k(const float* __restrict__ d7, float* __restrict__ out) {
    int n = blockIdx.x * blockDim.x + threadIdx.x;
    if (n >= 88) return;
    const float* p = d7 + (size_t)n * TT;
    float* q = out + (size_t)n * TT;
    q[0] = 0.f;                        // final delay_shift zero-pads t=0
    float u = 0.f, v = 0.f;
    int refc = 0;
    for (int t = 0; t < TT; ++t) {
        float xt = p[t];
        u = __fadd_rn(__fmul_rn(u, DECAY_U), __fmul_rn(xt, 64.0f));
        float vn = __fadd_rn(__fmul_rn(v, DECAY_V), u);
        v = refc ? 0.0f : vn;
        float s = (v >= THETA) ? 1.0f : 0.0f;
        if (s > 0.f) { refc = 1; v = 0.f; }
        else         { refc = refc > 0 ? refc - 1 : 0; }
        if (t < TT - 1) q[t + 1] = s;  // shifted by 1
    }
}

extern "C" void kernel_launch(void* const* d_in, const int* in_sizes, int n_in,
                              void* d_out, int out_size, void* d_ws, size_t ws_size,
                              hipStream_t stream) {
    const float* x   = (const float*)d_in[0];
    const float* w1  = (const float*)d_in[1];
    const float* w2  = (const float*)d_in[2];
    const float* wf1 = (const float*)d_in[3];
    const float* wf2 = (const float*)d_in[4];
    float* out = (float*)d_out;

    float* ws = (float*)d_ws;
    // Region A: 4,194,304 floats | Region B: 16,777,216 floats | C: 11,264 floats
    float* A = ws;
    float* B = ws + 4194304;
    float* C = ws + 4194304 + 16777216;

    const int BS = 256;
    #define GRID(N) dim3(((N) + BS - 1) / BS)

    // L1: pool1 + LIF  (A = d1/s1, 2,097,152 elems, 16384 neurons)
    pool1_k<<<GRID(2097152), BS, 0, stream>>>(x, A);
    lif_k  <<<GRID(16384),   BS, 0, stream>>>(A, 16384);

    // L2: conv1 + LIF  (B = d2/s2, 16,777,216 elems, 131072 neurons)
    conv1_k<<<GRID(16777216), BS, 0, stream>>>(A, w1, B);
    lif_k  <<<GRID(131072),   BS, 0, stream>>>(B, 131072);

    // L3: pool2 + LIF  (A = d3/s3, 4,194,304 elems, 32768 neurons)
    pool2_k<<<GRID(4194304), BS, 0, stream>>>(B, A);
    lif_k  <<<GRID(32768),   BS, 0, stream>>>(A, 32768);

    // L4: conv2 + LIF  (B = d4/s4, 8,388,608 elems, 65536 neurons)
    conv2_k<<<GRID(8388608), BS, 0, stream>>>(A, w2, B);
    lif_k  <<<GRID(65536),   BS, 0, stream>>>(B, 65536);

    // L5: pool3 + LIF  (A = d5/s5, 2,097,152 elems, 16384 neurons)
    pool3_k<<<GRID(2097152), BS, 0, stream>>>(B, A);
    lif_k  <<<GRID(16384),   BS, 0, stream>>>(A, 16384);

    // L6: fc1 + LIF   (B = d6/s6, 524,288 elems, 4096 neurons)
    fc1_k<<<GRID(65536), BS, 0, stream>>>(A, wf1, B);
    lif_k<<<GRID(4096),  BS, 0, stream>>>(B, 4096);

    // L7: fc2 drive + LIF + final shift -> d_out
    fc2_k    <<<GRID(11264), BS, 0, stream>>>(B, wf2, C);
    lif_out_k<<<1, 128, 0, stream>>>(C, out);

    #undef GRID
}

// Round 2
// 478.931 us; speedup vs baseline: 2.0000x; 2.0000x over previous
//
#include <hip/hip_runtime.h>

#define TT 128

// LIF constants
#define DECAY_U 0.75f
#define DECAY_V 0.96875f
#define THETA   5120.0f
#define POOLW   88.0f

// ---------------- Layer 1: sum_pool(x,4)*88, no delay ----------------
// x: [8,2,128,128,128] -> d1: [8,2,32,32,128]
__global__ void pool1_k(const float* __restrict__ x, float* __restrict__ d1) {
    int id = blockIdx.x * blockDim.x + threadIdx.x;
    int t = id & 127;
    int n = id >> 7;
    int px = n & 31, py = (n >> 5) & 31, c = (n >> 10) & 1, b = n >> 11;
    const float* base = x + (size_t)((((b*2 + c)*128 + py*4)*128) + px*4) * 128 + t;
    float s = 0.f;
    #pragma unroll
    for (int dy = 0; dy < 4; ++dy)
        #pragma unroll
        for (int dx = 0; dx < 4; ++dx)
            s += base[(dy*128 + dx) * 128];
    d1[id] = s * POOLW;
}

// ---------------- Generic LIF, in place: drive -> spikes (float4, 4 steps/iter) ----
__device__ __forceinline__ void lif_step(float xt, float& u, float& v, int& refc, float& s) {
    u = __fadd_rn(__fmul_rn(u, DECAY_U), __fmul_rn(xt, 64.0f));
    float vn = __fadd_rn(__fmul_rn(v, DECAY_V), u);
    v = refc ? 0.0f : vn;
    s = (v >= THETA) ? 1.0f : 0.0f;
    if (s > 0.f) { refc = 1; v = 0.f; }
    else         { refc = refc > 0 ? refc - 1 : 0; }
}

__global__ void lif_k(float* __restrict__ buf, int N) {
    int n = blockIdx.x * blockDim.x + threadIdx.x;
    if (n >= N) return;
    float4* p = (float4*)(buf + (size_t)n * TT);
    float u = 0.f, v = 0.f;
    int refc = 0;
    #pragma unroll 4
    for (int i = 0; i < TT/4; ++i) {
        float4 x4 = p[i];
        float s0, s1, s2, s3;
        lif_step(x4.x, u, v, refc, s0);
        lif_step(x4.y, u, v, refc, s1);
        lif_step(x4.z, u, v, refc, s2);
        lif_step(x4.w, u, v, refc, s3);
        p[i] = make_float4(s0, s1, s2, s3);
    }
}

// ---------------- Layer 2: conv1 5x5 SAME, 2->16, input delayed ----------------
// s1: [8,2,32,32,128] -> d2: [8,16,32,32,128]
// thread = (b,py,px,t), computes all 16 oc. Weights in LDS transposed [ck][oc].
__global__ void conv1_k(const float* __restrict__ s1, const float* __restrict__ w1,
                        float* __restrict__ d2) {
    __shared__ float wT[50][16];
    for (int i = threadIdx.x; i < 800; i += 256) {
        int oc = i / 50, ck = i % 50;
        wT[ck][oc] = w1[oc * 50 + ck];
    }
    __syncthreads();
    int id = blockIdx.x * 256 + threadIdx.x;
    int t = id & 127;
    int n = id >> 7;
    int px = n & 31, py = (n >> 5) & 31, b = n >> 10;
    float acc[16];
    #pragma unroll
    for (int k = 0; k < 16; ++k) acc[k] = 0.f;
    if (t > 0) {
        const float* sp = s1 + (size_t)(b*2) * 32 * 32 * 128 + (t - 1);
        #pragma unroll
        for (int c = 0; c < 2; ++c) {
            const float* ip = sp + (size_t)c * 32 * 32 * 128;
            #pragma unroll
            for (int ky = 0; ky < 5; ++ky) {
                int iy = py + ky - 2;
                if ((unsigned)iy >= 32u) continue;
                #pragma unroll
                for (int kx = 0; kx < 5; ++kx) {
                    int ix = px + kx - 2;
                    if ((unsigned)ix >= 32u) continue;
                    float v = ip[(iy*32 + ix) * 128];
                    const float4* wv = (const float4*)wT[c*25 + ky*5 + kx];
                    #pragma unroll
                    for (int j = 0; j < 4; ++j) {
                        float4 w = wv[j];
                        acc[j*4+0] = fmaf(w.x, v, acc[j*4+0]);
                        acc[j*4+1] = fmaf(w.y, v, acc[j*4+1]);
                        acc[j*4+2] = fmaf(w.z, v, acc[j*4+2]);
                        acc[j*4+3] = fmaf(w.w, v, acc[j*4+3]);
                    }
                }
            }
        }
    }
    size_t obase = (((size_t)(b*16) * 32 + py) * 32 + px) * 128 + t;
    #pragma unroll
    for (int oc = 0; oc < 16; ++oc)
        d2[obase + (size_t)oc * 32 * 32 * 128] = acc[oc];
}

// ---------------- Layer 3: sum_pool(s2,2)*88, delayed ----------------
__global__ void pool2_k(const float* __restrict__ s2, float* __restrict__ d3) {
    int id = blockIdx.x * blockDim.x + threadIdx.x;
    int t = id & 127;
    int n = id >> 7;
    int px = n & 15, py = (n >> 4) & 15, c = (n >> 8) & 15, b = n >> 12;
    float acc = 0.f;
    if (t > 0) {
        const float* ip = s2 + (size_t)(((b*16 + c)*32 + py*2)*32 + px*2) * 128 + (t - 1);
        acc = (ip[0] + ip[128] + ip[32*128] + ip[33*128]) * POOLW;
    }
    d3[id] = acc;
}

// ---------------- Layer 4: conv2 3x3 SAME, 16->32, delayed ----------------
// s3: [8,16,16,16,128] -> d4: [8,32,16,16,128]
// thread = (b,py,px,t), computes all 32 oc. Weights in LDS transposed [ck][oc].
__global__ void conv2_k(const float* __restrict__ s3, const float* __restrict__ w2,
                        float* __restrict__ d4) {
    __shared__ float wT[144][32];
    for (int i = threadIdx.x; i < 4608; i += 256) {
        int oc = i / 144, ck = i % 144;
        wT[ck][oc] = w2[oc * 144 + ck];
    }
    __syncthreads();
    int id = blockIdx.x * 256 + threadIdx.x;
    int t = id & 127;
    int n = id >> 7;
    int px = n & 15, py = (n >> 4) & 15, b = n >> 8;
    float acc[32];
    #pragma unroll
    for (int k = 0; k < 32; ++k) acc[k] = 0.f;
    if (t > 0) {
        const float* sp = s3 + (size_t)(b*16) * 16 * 16 * 128 + (t - 1);
        for (int c = 0; c < 16; ++c) {
            const float* ip = sp + (size_t)c * 16 * 16 * 128;
            #pragma unroll
            for (int ky = 0; ky < 3; ++ky) {
                int iy = py + ky - 1;
                if ((unsigned)iy >= 16u) continue;
                #pragma unroll
                for (int kx = 0; kx < 3; ++kx) {
                    int ix = px + kx - 1;
                    if ((unsigned)ix >= 16u) continue;
                    float v = ip[(iy*16 + ix) * 128];
                    const float4* wv = (const float4*)wT[c*9 + ky*3 + kx];
                    #pragma unroll
                    for (int j = 0; j < 8; ++j) {
                        float4 w = wv[j];
                        acc[j*4+0] = fmaf(w.x, v, acc[j*4+0]);
                        acc[j*4+1] = fmaf(w.y, v, acc[j*4+1]);
                        acc[j*4+2] = fmaf(w.z, v, acc[j*4+2]);
                        acc[j*4+3] = fmaf(w.w, v, acc[j*4+3]);
                    }
                }
            }
        }
    }
    size_t obase = (((size_t)(b*32) * 16 + py) * 16 + px) * 128 + t;
    #pragma unroll
    for (int oc = 0; oc < 32; ++oc)
        d4[obase + (size_t)oc * 16 * 16 * 128] = acc[oc];
}

// ---------------- Layer 5: sum_pool(s4,2)*88, delayed ----------------
__global__ void pool3_k(const float* __restrict__ s4, float* __restrict__ d5) {
    int id = blockIdx.x * blockDim.x + threadIdx.x;
    int t = id & 127;
    int n = id >> 7;
    int px = n & 7, py = (n >> 3) & 7, c = (n >> 6) & 31, b = n >> 11;
    float acc = 0.f;
    if (t > 0) {
        const float* ip = s4 + (size_t)(((b*32 + c)*16 + py*2)*16 + px*2) * 128 + (t - 1);
        acc = (ip[0] + ip[128] + ip[16*128] + ip[17*128]) * POOLW;
    }
    d5[id] = acc;
}

// ---------------- Layer 6: fc1 2048->512, delayed ----------------
// s5: [8,2048,128] -> d6: [8,512,128]; 8 outputs/thread, float4 weight loads
__global__ void fc1_k(const float* __restrict__ s5, const float* __restrict__ wf1,
                      float* __restrict__ d6) {
    int id = blockIdx.x * blockDim.x + threadIdx.x;
    int t = id & 127;
    int n = id >> 7;
    int og = n & 63, b = n >> 6;
    float acc[8] = {0.f, 0.f, 0.f, 0.f, 0.f, 0.f, 0.f, 0.f};
    if (t > 0) {
        const float* sp = s5 + (size_t)b * 2048 * 128 + (t - 1);
        for (int f = 0; f < 2048; f += 4) {
            float s0 = sp[(size_t)f * 128];
            float s1 = sp[(size_t)(f+1) * 128];
            float s2 = sp[(size_t)(f+2) * 128];
            float s3 = sp[(size_t)(f+3) * 128];
            #pragma unroll
            for (int k = 0; k < 8; ++k) {
                float4 w = *(const float4*)&wf1[(size_t)(og + k*64) * 2048 + f];
                acc[k] = fmaf(w.x, s0, acc[k]);
                acc[k] = fmaf(w.y, s1, acc[k]);
                acc[k] = fmaf(w.z, s2, acc[k]);
                acc[k] = fmaf(w.w, s3, acc[k]);
            }
        }
    }
    #pragma unroll
    for (int k = 0; k < 8; ++k)
        d6[((size_t)(b*512 + og + k*64)) * 128 + t] = acc[k];
}

// ---------------- Layer 7 drive: fc2 512->11, delayed ----------------
__global__ void fc2_k(const float* __restrict__ s6, const float* __restrict__ wf2,
                      float* __restrict__ d7) {
    int id = blockIdx.x * blockDim.x + threadIdx.x;
    int t = id & 127;
    int n = id >> 7;
    int o = n % 11, b = n / 11;
    float acc = 0.f;
    if (t > 0) {
        const float* sp = s6 + (size_t)b * 512 * 128 + (t - 1);
        const float* wp = wf2 + o * 512;
        for (int f = 0; f < 512; f += 4) {
            float4 w = *(const float4*)&wp[f];
            acc = fmaf(w.x, sp[(size_t)f * 128], acc);
            acc = fmaf(w.y, sp[(size_t)(f+1) * 128], acc);
            acc = fmaf(w.z, sp[(size_t)(f+2) * 128], acc);
            acc = fmaf(w.w, sp[(size_t)(f+3) * 128], acc);
        }
    }
    d7[id] = acc;
}

// ---------------- Layer 7 LIF + final delay_shift, writes d_out ----------------
__global__ void lif_out_k(const float* __restrict__ d7, float* __restrict__ out) {
    int n = blockIdx.x * blockDim.x + threadIdx.x;
    if (n >= 88) return;
    const float* p = d7 + (size_t)n * TT;
    float* q = out + (size_t)n * TT;
    q[0] = 0.f;
    float u = 0.f, v = 0.f;
    int refc = 0;
    for (int t = 0; t < TT; ++t) {
        float s;
        lif_step(p[t], u, v, refc, s);
        if (t < TT - 1) q[t + 1] = s;
    }
}

extern "C" void kernel_launch(void* const* d_in, const int* in_sizes, int n_in,
                              void* d_out, int out_size, void* d_ws, size_t ws_size,
                              hipStream_t stream) {
    const float* x   = (const float*)d_in[0];
    const float* w1  = (const float*)d_in[1];
    const float* w2  = (const float*)d_in[2];
    const float* wf1 = (const float*)d_in[3];
    const float* wf2 = (const float*)d_in[4];
    float* out = (float*)d_out;

    float* ws = (float*)d_ws;
    float* A = ws;                       // 4,194,304 floats
    float* B = ws + 4194304;             // 16,777,216 floats
    float* C = ws + 4194304 + 16777216;  // 11,264 floats

    const int BS = 256;
    #define GRID(N) dim3(((N) + BS - 1) / BS)

    // L1: pool1 + LIF  (A = d1/s1: [8,2,32,32,128])
    pool1_k<<<GRID(2097152), BS, 0, stream>>>(x, A);
    lif_k  <<<GRID(16384),   BS, 0, stream>>>(A, 16384);

    // L2: conv1 (16 oc/thread) + LIF  (B = d2/s2: [8,16,32,32,128])
    conv1_k<<<dim3(4096), BS, 0, stream>>>(A, w1, B);
    lif_k  <<<GRID(131072), BS, 0, stream>>>(B, 131072);

    // L3: pool2 + LIF  (A = d3/s3: [8,16,16,16,128])
    pool2_k<<<GRID(4194304), BS, 0, stream>>>(B, A);
    lif_k  <<<GRID(32768),   BS, 0, stream>>>(A, 32768);

    // L4: conv2 (32 oc/thread) + LIF  (B = d4/s4: [8,32,16,16,128])
    conv2_k<<<dim3(1024), BS, 0, stream>>>(A, w2, B);
    lif_k  <<<GRID(65536), BS, 0, stream>>>(B, 65536);

    // L5: pool3 + LIF  (A = d5/s5: [8,32,8,8,128] = [8,2048,128])
    pool3_k<<<GRID(2097152), BS, 0, stream>>>(B, A);
    lif_k  <<<GRID(16384),   BS, 0, stream>>>(A, 16384);

    // L6: fc1 + LIF   (B = d6/s6: [8,512,128])
    fc1_k<<<GRID(65536), BS, 0, stream>>>(A, wf1, B);
    lif_k<<<GRID(4096),  BS, 0, stream>>>(B, 4096);

    // L7: fc2 drive + LIF + final shift -> d_out
    fc2_k    <<<GRID(11264), BS, 0, stream>>>(B, wf2, C);
    lif_out_k<<<1, 128, 0, stream>>>(C, out);

    #undef GRID
}

// Round 3
// 309.095 us; speedup vs baseline: 3.0989x; 1.5495x over previous
//
#include <hip/hip_runtime.h>

#define TT 128

// LIF constants
#define DECAY_U 0.75f
#define DECAY_V 0.96875f
#define THETA   5120.0f
#define POOLW   88.0f

// ---------------- Layer 1: sum_pool(x,4)*88, no delay ----------------
__global__ void pool1_k(const float* __restrict__ x, float* __restrict__ d1) {
    int id = blockIdx.x * blockDim.x + threadIdx.x;
    int t = id & 127;
    int n = id >> 7;
    int px = n & 31, py = (n >> 5) & 31, c = (n >> 10) & 1, b = n >> 11;
    const float* base = x + (size_t)((((b*2 + c)*128 + py*4)*128) + px*4) * 128 + t;
    float s = 0.f;
    #pragma unroll
    for (int dy = 0; dy < 4; ++dy)
        #pragma unroll
        for (int dx = 0; dx < 4; ++dx)
            s += base[(dy*128 + dx) * 128];
    d1[id] = s * POOLW;
}

// ---------------- Generic LIF, in place ----------------
__device__ __forceinline__ void lif_step(float xt, float& u, float& v, int& refc, float& s) {
    u = __fadd_rn(__fmul_rn(u, DECAY_U), __fmul_rn(xt, 64.0f));
    float vn = __fadd_rn(__fmul_rn(v, DECAY_V), u);
    v = refc ? 0.0f : vn;
    s = (v >= THETA) ? 1.0f : 0.0f;
    if (s > 0.f) { refc = 1; v = 0.f; }
    else         { refc = refc > 0 ? refc - 1 : 0; }
}

__global__ void lif_k(float* __restrict__ buf, int N) {
    int n = blockIdx.x * blockDim.x + threadIdx.x;
    if (n >= N) return;
    float4* p = (float4*)(buf + (size_t)n * TT);
    float u = 0.f, v = 0.f;
    int refc = 0;
    #pragma unroll 4
    for (int i = 0; i < TT/4; ++i) {
        float4 x4 = p[i];
        float s0, s1, s2, s3;
        lif_step(x4.x, u, v, refc, s0);
        lif_step(x4.y, u, v, refc, s1);
        lif_step(x4.z, u, v, refc, s2);
        lif_step(x4.w, u, v, refc, s3);
        p[i] = make_float4(s0, s1, s2, s3);
    }
}

// ---------------- Layer 2: conv1 5x5 SAME, 2->16, input delayed ----------------
__global__ void conv1_k(const float* __restrict__ s1, const float* __restrict__ w1,
                        float* __restrict__ d2) {
    __shared__ float wT[50][16];
    for (int i = threadIdx.x; i < 800; i += 256) {
        int oc = i / 50, ck = i % 50;
        wT[ck][oc] = w1[oc * 50 + ck];
    }
    __syncthreads();
    int id = blockIdx.x * 256 + threadIdx.x;
    int t = id & 127;
    int n = id >> 7;
    int px = n & 31, py = (n >> 5) & 31, b = n >> 10;
    float acc[16];
    #pragma unroll
    for (int k = 0; k < 16; ++k) acc[k] = 0.f;
    if (t > 0) {
        const float* sp = s1 + (size_t)(b*2) * 32 * 32 * 128 + (t - 1);
        #pragma unroll
        for (int c = 0; c < 2; ++c) {
            const float* ip = sp + (size_t)c * 32 * 32 * 128;
            #pragma unroll
            for (int ky = 0; ky < 5; ++ky) {
                int iy = py + ky - 2;
                if ((unsigned)iy >= 32u) continue;
                #pragma unroll
                for (int kx = 0; kx < 5; ++kx) {
                    int ix = px + kx - 2;
                    if ((unsigned)ix >= 32u) continue;
                    float v = ip[(iy*32 + ix) * 128];
                    const float4* wv = (const float4*)wT[c*25 + ky*5 + kx];
                    #pragma unroll
                    for (int j = 0; j < 4; ++j) {
                        float4 w = wv[j];
                        acc[j*4+0] = fmaf(w.x, v, acc[j*4+0]);
                        acc[j*4+1] = fmaf(w.y, v, acc[j*4+1]);
                        acc[j*4+2] = fmaf(w.z, v, acc[j*4+2]);
                        acc[j*4+3] = fmaf(w.w, v, acc[j*4+3]);
                    }
                }
            }
        }
    }
    size_t obase = (((size_t)(b*16) * 32 + py) * 32 + px) * 128 + t;
    #pragma unroll
    for (int oc = 0; oc < 16; ++oc)
        d2[obase + (size_t)oc * 32 * 32 * 128] = acc[oc];
}

// ---------------- Layer 3: sum_pool(s2,2)*88, delayed ----------------
__global__ void pool2_k(const float* __restrict__ s2, float* __restrict__ d3) {
    int id = blockIdx.x * blockDim.x + threadIdx.x;
    int t = id & 127;
    int n = id >> 7;
    int px = n & 15, py = (n >> 4) & 15, c = (n >> 8) & 15, b = n >> 12;
    float acc = 0.f;
    if (t > 0) {
        const float* ip = s2 + (size_t)(((b*16 + c)*32 + py*2)*32 + px*2) * 128 + (t - 1);
        acc = (ip[0] + ip[128] + ip[32*128] + ip[33*128]) * POOLW;
    }
    d3[id] = acc;
}

// ---------------- Layer 4: conv2 3x3 SAME, 16->32, delayed ----------------
__global__ void conv2_k(const float* __restrict__ s3, const float* __restrict__ w2,
                        float* __restrict__ d4) {
    __shared__ float wT[144][32];
    for (int i = threadIdx.x; i < 4608; i += 256) {
        int oc = i / 144, ck = i % 144;
        wT[ck][oc] = w2[oc * 144 + ck];
    }
    __syncthreads();
    int id = blockIdx.x * 256 + threadIdx.x;
    int t = id & 127;
    int n = id >> 7;
    int px = n & 15, py = (n >> 4) & 15, b = n >> 8;
    float acc[32];
    #pragma unroll
    for (int k = 0; k < 32; ++k) acc[k] = 0.f;
    if (t > 0) {
        const float* sp = s3 + (size_t)(b*16) * 16 * 16 * 128 + (t - 1);
        for (int c = 0; c < 16; ++c) {
            const float* ip = sp + (size_t)c * 16 * 16 * 128;
            #pragma unroll
            for (int ky = 0; ky < 3; ++ky) {
                int iy = py + ky - 1;
                if ((unsigned)iy >= 16u) continue;
                #pragma unroll
                for (int kx = 0; kx < 3; ++kx) {
                    int ix = px + kx - 1;
                    if ((unsigned)ix >= 16u) continue;
                    float v = ip[(iy*16 + ix) * 128];
                    const float4* wv = (const float4*)wT[c*9 + ky*3 + kx];
                    #pragma unroll
                    for (int j = 0; j < 8; ++j) {
                        float4 w = wv[j];
                        acc[j*4+0] = fmaf(w.x, v, acc[j*4+0]);
                        acc[j*4+1] = fmaf(w.y, v, acc[j*4+1]);
                        acc[j*4+2] = fmaf(w.z, v, acc[j*4+2]);
                        acc[j*4+3] = fmaf(w.w, v, acc[j*4+3]);
                    }
                }
            }
        }
    }
    size_t obase = (((size_t)(b*32) * 16 + py) * 16 + px) * 128 + t;
    #pragma unroll
    for (int oc = 0; oc < 32; ++oc)
        d4[obase + (size_t)oc * 16 * 16 * 128] = acc[oc];
}

// ---------------- Layer 5: sum_pool(s4,2)*88, delayed ----------------
__global__ void pool3_k(const float* __restrict__ s4, float* __restrict__ d5) {
    int id = blockIdx.x * blockDim.x + threadIdx.x;
    int t = id & 127;
    int n = id >> 7;
    int px = n & 7, py = (n >> 3) & 7, c = (n >> 6) & 31, b = n >> 11;
    float acc = 0.f;
    if (t > 0) {
        const float* ip = s4 + (size_t)(((b*32 + c)*16 + py*2)*16 + px*2) * 128 + (t - 1);
        acc = (ip[0] + ip[128] + ip[16*128] + ip[17*128]) * POOLW;
    }
    d5[id] = acc;
}

// ---------------- Layer 6: fc1 as tiled K-split GEMM ----------------
// Per b: C[512,128] = W[512,2048] x S[2048,128] (S column shifted by 1 in t).
// Block: 64 outputs x 64 t x 256 K, 4 k-steps of 64. Grid = 8kc x 8ot x 2tt x 8b.
// part[kc][b*512+o][t]
__global__ __launch_bounds__(256) void fc1_gemm_k(const float* __restrict__ s5,
                                                  const float* __restrict__ wf1,
                                                  float* __restrict__ part) {
    __shared__ float WT[64][68];  // [f_local][o_local]
    __shared__ float ST[64][68];  // [f_local][t_local]
    int bid = blockIdx.x;
    int kc = bid & 7;
    int ot = (bid >> 3) & 7;
    int tt = (bid >> 6) & 1;
    int b  = bid >> 7;
    int tid = threadIdx.x;
    int oo = tid >> 4;       // 0..15, 4 outputs each
    int to = tid & 15;       // 0..15, 4 t each

    const float* wbase = wf1 + (size_t)(ot*64) * 2048 + kc*256;
    const float* sbase = s5 + (size_t)b * 262144 + (size_t)(kc*256) * 128;

    float acc[4][4];
    #pragma unroll
    for (int i = 0; i < 4; ++i)
        #pragma unroll
        for (int j = 0; j < 4; ++j) acc[i][j] = 0.f;

    for (int ks = 0; ks < 4; ++ks) {
        __syncthreads();
        // stage W tile [64 o][64 f] -> WT[f][o]
        #pragma unroll
        for (int i = 0; i < 4; ++i) {
            int e = tid + 256*i;            // 0..1023, covers 64x64 via 4B each? need 4096
            int o = e >> 6;                 // 0..15 per pass
            int f = e & 63;
            // each pass covers 16 o rows; 4 passes -> 64 rows via o + 16*i? redo:
            (void)o; (void)f;
        }
        // simpler: 4096 elems, 256 threads, 16 each, linear
        #pragma unroll
        for (int i = 0; i < 16; ++i) {
            int e = tid + 256*i;
            int o = e >> 6, f = e & 63;
            WT[f][o] = wbase[(size_t)o * 2048 + ks*64 + f];
        }
        // stage S tile: ST[f][tl] = s5[f][tt*64+tl-1] (0 when t==0)
        #pragma unroll
        for (int i = 0; i < 16; ++i) {
            int e = tid + 256*i;
            int f = e >> 6, tl = e & 63;
            int tsrc = tt*64 + tl - 1;
            ST[f][tl] = (tsrc < 0) ? 0.f : sbase[(size_t)f * 128 + ks*64*128 + tsrc];
        }
        __syncthreads();
        #pragma unroll 4
        for (int k = 0; k < 64; ++k) {
            float4 a = *(const float4*)&WT[k][oo*4];
            float4 s = *(const float4*)&ST[k][to*4];
            acc[0][0] = fmaf(a.x, s.x, acc[0][0]);
            acc[0][1] = fmaf(a.x, s.y, acc[0][1]);
            acc[0][2] = fmaf(a.x, s.z, acc[0][2]);
            acc[0][3] = fmaf(a.x, s.w, acc[0][3]);
            acc[1][0] = fmaf(a.y, s.x, acc[1][0]);
            acc[1][1] = fmaf(a.y, s.y, acc[1][1]);
            acc[1][2] = fmaf(a.y, s.z, acc[1][2]);
            acc[1][3] = fmaf(a.y, s.w, acc[1][3]);
            acc[2][0] = fmaf(a.z, s.x, acc[2][0]);
            acc[2][1] = fmaf(a.z, s.y, acc[2][1]);
            acc[2][2] = fmaf(a.z, s.z, acc[2][2]);
            acc[2][3] = fmaf(a.z, s.w, acc[2][3]);
            acc[3][0] = fmaf(a.w, s.x, acc[3][0]);
            acc[3][1] = fmaf(a.w, s.y, acc[3][1]);
            acc[3][2] = fmaf(a.w, s.z, acc[3][2]);
            acc[3][3] = fmaf(a.w, s.w, acc[3][3]);
        }
    }
    float* pb = part + (size_t)kc * 524288 + (size_t)b * 65536
              + (size_t)(ot*64 + oo*4) * 128 + tt*64 + to*4;
    #pragma unroll
    for (int i = 0; i < 4; ++i)
        #pragma unroll
        for (int j = 0; j < 4; ++j)
            pb[(size_t)i * 128 + j] = acc[i][j];
}

// Sum 8 K-chunk partials in fixed order -> d6 [8,512,128]
__global__ void fc1_reduce_k(const float* __restrict__ part, float* __restrict__ d6) {
    int id = blockIdx.x * blockDim.x + threadIdx.x;  // 131072, float4 each
    float4 s = make_float4(0.f, 0.f, 0.f, 0.f);
    #pragma unroll
    for (int kc = 0; kc < 8; ++kc) {
        float4 p = *(const float4*)&part[(size_t)kc * 524288 + (size_t)id * 4];
        s.x += p.x; s.y += p.y; s.z += p.z; s.w += p.w;
    }
    *(float4*)&d6[(size_t)id * 4] = s;
}

// ---------------- Layer 7 drive: fc2 512->11, delayed ----------------
__global__ void fc2_k(const float* __restrict__ s6, const float* __restrict__ wf2,
                      float* __restrict__ d7) {
    int id = blockIdx.x * blockDim.x + threadIdx.x;
    int t = id & 127;
    int n = id >> 7;
    int o = n % 11, b = n / 11;
    float acc = 0.f;
    if (t > 0) {
        const float* sp = s6 + (size_t)b * 512 * 128 + (t - 1);
        const float* wp = wf2 + o * 512;
        for (int f = 0; f < 512; f += 4) {
            float4 w = *(const float4*)&wp[f];
            acc = fmaf(w.x, sp[(size_t)f * 128], acc);
            acc = fmaf(w.y, sp[(size_t)(f+1) * 128], acc);
            acc = fmaf(w.z, sp[(size_t)(f+2) * 128], acc);
            acc = fmaf(w.w, sp[(size_t)(f+3) * 128], acc);
        }
    }
    d7[id] = acc;
}

// ---------------- Layer 7 LIF + final delay_shift ----------------
__global__ void lif_out_k(const float* __restrict__ d7, float* __restrict__ out) {
    int n = blockIdx.x * blockDim.x + threadIdx.x;
    if (n >= 88) return;
    const float* p = d7 + (size_t)n * TT;
    float* q = out + (size_t)n * TT;
    q[0] = 0.f;
    float u = 0.f, v = 0.f;
    int refc = 0;
    for (int t = 0; t < TT; ++t) {
        float s;
        lif_step(p[t], u, v, refc, s);
        if (t < TT - 1) q[t + 1] = s;
    }
}

extern "C" void kernel_launch(void* const* d_in, const int* in_sizes, int n_in,
                              void* d_out, int out_size, void* d_ws, size_t ws_size,
                              hipStream_t stream) {
    const float* x   = (const float*)d_in[0];
    const float* w1  = (const float*)d_in[1];
    const float* w2  = (const float*)d_in[2];
    const float* wf1 = (const float*)d_in[3];
    const float* wf2 = (const float*)d_in[4];
    float* out = (float*)d_out;

    float* ws = (float*)d_ws;
    float* A = ws;                       // 4,194,304 floats
    float* B = ws + 4194304;             // 16,777,216 floats
    float* C = ws + 4194304 + 16777216;  // 11,264 floats
    float* PART = B + 1048576;           // 4,194,304 floats (inside B, after d6)

    const int BS = 256;
    #define GRID(N) dim3(((N) + BS - 1) / BS)

    // L1: pool1 + LIF  (A = d1/s1: [8,2,32,32,128])
    pool1_k<<<GRID(2097152), BS, 0, stream>>>(x, A);
    lif_k  <<<GRID(16384),   BS, 0, stream>>>(A, 16384);

    // L2: conv1 + LIF  (B = d2/s2: [8,16,32,32,128])
    conv1_k<<<dim3(4096), BS, 0, stream>>>(A, w1, B);
    lif_k  <<<GRID(131072), BS, 0, stream>>>(B, 131072);

    // L3: pool2 + LIF  (A = d3/s3: [8,16,16,16,128])
    pool2_k<<<GRID(4194304), BS, 0, stream>>>(B, A);
    lif_k  <<<GRID(32768),   BS, 0, stream>>>(A, 32768);

    // L4: conv2 + LIF  (B = d4/s4: [8,32,16,16,128])
    conv2_k<<<dim3(1024), BS, 0, stream>>>(A, w2, B);
    lif_k  <<<GRID(65536), BS, 0, stream>>>(B, 65536);

    // L5: pool3 + LIF  (A = d5/s5: [8,32,8,8,128] = [8,2048,128])
    pool3_k<<<GRID(2097152), BS, 0, stream>>>(B, A);
    lif_k  <<<GRID(16384),   BS, 0, stream>>>(A, 16384);

    // L6: fc1 tiled GEMM (A -> PART) + reduce (-> B) + LIF
    fc1_gemm_k  <<<dim3(1024), BS, 0, stream>>>(A, wf1, PART);
    fc1_reduce_k<<<GRID(131072), BS, 0, stream>>>(PART, B);
    lif_k       <<<GRID(4096),   BS, 0, stream>>>(B, 4096);

    // L7: fc2 drive + LIF + final shift -> d_out
    fc2_k    <<<GRID(11264), BS, 0, stream>>>(B, wf2, C);
    lif_out_k<<<1, 128, 0, stream>>>(C, out);

    #undef GRID
}

// Round 4
// 282.810 us; speedup vs baseline: 3.3869x; 1.0929x over previous
//
#include <hip/hip_runtime.h>

#define TT 128

// LIF constants
#define DECAY_U 0.75f
#define DECAY_V 0.96875f
#define THETA   5120.0f
#define POOLW   88.0f

__device__ __forceinline__ void lif_step(float xt, float& u, float& v, int& refc, float& s) {
    u = __fadd_rn(__fmul_rn(u, DECAY_U), __fmul_rn(xt, 64.0f));
    float vn = __fadd_rn(__fmul_rn(v, DECAY_V), u);
    v = refc ? 0.0f : vn;
    s = (v >= THETA) ? 1.0f : 0.0f;
    if (s > 0.f) { refc = 1; v = 0.f; }
    else         { refc = refc > 0 ? refc - 1 : 0; }
}

// Serial LIF over an LDS column: col[t*stride], t=0..127. Loads are
// state-independent -> compiler issues them ahead of the dependent chain.
__device__ __forceinline__ void lif_seq_lds(float* col, int stride) {
    float u = 0.f, v = 0.f;
    int refc = 0;
    #pragma unroll 16
    for (int t = 0; t < TT; ++t) {
        float s;
        lif_step(col[t * stride], u, v, refc, s);
        col[t * stride] = s;
    }
}

// ---------------- L1: sum_pool(x,4)*88 + LIF ----------------
// x: [8,2,128,128,128] -> s1: [8,2,32,32,128]; block = 2 neurons x 128 t
__global__ void pool1_lif_k(const float* __restrict__ x, float* __restrict__ s1) {
    __shared__ float sb[TT][3];
    int t = threadIdx.x & 127, pos = threadIdx.x >> 7;
    int n = blockIdx.x * 2 + pos;
    int px = n & 31, py = (n >> 5) & 31, c = (n >> 10) & 1, b = n >> 11;
    const float* base = x + (size_t)((((b*2 + c)*128 + py*4)*128) + px*4) * 128 + t;
    float s = 0.f;
    #pragma unroll
    for (int dy = 0; dy < 4; ++dy)
        #pragma unroll
        for (int dx = 0; dx < 4; ++dx)
            s += base[(dy*128 + dx) * 128];
    sb[t][pos] = s * POOLW;
    __syncthreads();
    if (threadIdx.x < 2) lif_seq_lds(&sb[0][threadIdx.x], 3);
    __syncthreads();
    s1[(size_t)n * TT + t] = sb[t][pos];
}

// ---------------- L2: conv1 5x5 SAME 2->16 (input delayed) + LIF ----------------
// s1: [8,2,32,32,128] -> s2: [8,16,32,32,128]; block = 2 pos x 128 t, 16 oc/thread
__global__ void conv1_lif_k(const float* __restrict__ s1, const float* __restrict__ w1,
                            float* __restrict__ s2) {
    __shared__ float wT[50][16];
    __shared__ float sb[TT][33];   // [t][nl], nl = oc*2+pos
    for (int i = threadIdx.x; i < 800; i += 256) {
        int oc = i / 50, ck = i % 50;
        wT[ck][oc] = w1[oc * 50 + ck];
    }
    __syncthreads();
    int id = blockIdx.x * 256 + threadIdx.x;
    int t = id & 127, pos = threadIdx.x >> 7;
    int n = id >> 7;
    int px = n & 31, py = (n >> 5) & 31, b = n >> 10;
    float acc[16];
    #pragma unroll
    for (int k = 0; k < 16; ++k) acc[k] = 0.f;
    if (t > 0) {
        const float* sp = s1 + (size_t)(b*2) * 32 * 32 * 128 + (t - 1);
        #pragma unroll
        for (int c = 0; c < 2; ++c) {
            const float* ip = sp + (size_t)c * 32 * 32 * 128;
            #pragma unroll
            for (int ky = 0; ky < 5; ++ky) {
                int iy = py + ky - 2;
                if ((unsigned)iy >= 32u) continue;
                #pragma unroll
                for (int kx = 0; kx < 5; ++kx) {
                    int ix = px + kx - 2;
                    if ((unsigned)ix >= 32u) continue;
                    float v = ip[(iy*32 + ix) * 128];
                    const float4* wv = (const float4*)wT[c*25 + ky*5 + kx];
                    #pragma unroll
                    for (int j = 0; j < 4; ++j) {
                        float4 w = wv[j];
                        acc[j*4+0] = fmaf(w.x, v, acc[j*4+0]);
                        acc[j*4+1] = fmaf(w.y, v, acc[j*4+1]);
                        acc[j*4+2] = fmaf(w.z, v, acc[j*4+2]);
                        acc[j*4+3] = fmaf(w.w, v, acc[j*4+3]);
                    }
                }
            }
        }
    }
    #pragma unroll
    for (int oc = 0; oc < 16; ++oc) sb[t][oc*2 + pos] = acc[oc];
    __syncthreads();
    if (threadIdx.x < 32) lif_seq_lds(&sb[0][threadIdx.x], 33);
    __syncthreads();
    size_t obase = (((size_t)(b*16) * 32 + py) * 32 + px) * 128 + t;
    #pragma unroll
    for (int oc = 0; oc < 16; ++oc)
        s2[obase + (size_t)oc * 32 * 32 * 128] = sb[t][oc*2 + pos];
}

// ---------------- L3: sum_pool(s2,2)*88 (delayed) + LIF ----------------
// s2: [8,16,32,32,128] -> s3: [8,16,16,16,128]
__global__ void pool2_lif_k(const float* __restrict__ s2, float* __restrict__ s3) {
    __shared__ float sb[TT][3];
    int t = threadIdx.x & 127, pos = threadIdx.x >> 7;
    int n = blockIdx.x * 2 + pos;
    int px = n & 15, py = (n >> 4) & 15, c = (n >> 8) & 15, b = n >> 12;
    float acc = 0.f;
    if (t > 0) {
        const float* ip = s2 + (size_t)(((b*16 + c)*32 + py*2)*32 + px*2) * 128 + (t - 1);
        acc = (ip[0] + ip[128] + ip[32*128] + ip[33*128]) * POOLW;
    }
    sb[t][pos] = acc;
    __syncthreads();
    if (threadIdx.x < 2) lif_seq_lds(&sb[0][threadIdx.x], 3);
    __syncthreads();
    s3[(size_t)n * TT + t] = sb[t][pos];
}

// ---------------- L4: conv2 3x3 SAME 16->32 (delayed) + LIF ----------------
// s3: [8,16,16,16,128] -> s4: [8,32,16,16,128]; block = 2 pos x 128 t, 32 oc/thread
__global__ void conv2_lif_k(const float* __restrict__ s3, const float* __restrict__ w2,
                            float* __restrict__ s4) {
    __shared__ float wT[144][32];
    __shared__ float sb[TT][65];   // [t][nl], nl = oc*2+pos
    for (int i = threadIdx.x; i < 4608; i += 256) {
        int oc = i / 144, ck = i % 144;
        wT[ck][oc] = w2[oc * 144 + ck];
    }
    __syncthreads();
    int id = blockIdx.x * 256 + threadIdx.x;
    int t = id & 127, pos = threadIdx.x >> 7;
    int n = id >> 7;
    int px = n & 15, py = (n >> 4) & 15, b = n >> 8;
    float acc[32];
    #pragma unroll
    for (int k = 0; k < 32; ++k) acc[k] = 0.f;
    if (t > 0) {
        const float* sp = s3 + (size_t)(b*16) * 16 * 16 * 128 + (t - 1);
        for (int c = 0; c < 16; ++c) {
            const float* ip = sp + (size_t)c * 16 * 16 * 128;
            #pragma unroll
            for (int ky = 0; ky < 3; ++ky) {
                int iy = py + ky - 1;
                if ((unsigned)iy >= 16u) continue;
                #pragma unroll
                for (int kx = 0; kx < 3; ++kx) {
                    int ix = px + kx - 1;
                    if ((unsigned)ix >= 16u) continue;
                    float v = ip[(iy*16 + ix) * 128];
                    const float4* wv = (const float4*)wT[c*9 + ky*3 + kx];
                    #pragma unroll
                    for (int j = 0; j < 8; ++j) {
                        float4 w = wv[j];
                        acc[j*4+0] = fmaf(w.x, v, acc[j*4+0]);
                        acc[j*4+1] = fmaf(w.y, v, acc[j*4+1]);
                        acc[j*4+2] = fmaf(w.z, v, acc[j*4+2]);
                        acc[j*4+3] = fmaf(w.w, v, acc[j*4+3]);
                    }
                }
            }
        }
    }
    #pragma unroll
    for (int oc = 0; oc < 32; ++oc) sb[t][oc*2 + pos] = acc[oc];
    __syncthreads();
    if (threadIdx.x < 64) lif_seq_lds(&sb[0][threadIdx.x], 65);
    __syncthreads();
    size_t obase = (((size_t)(b*32) * 16 + py) * 16 + px) * 128 + t;
    #pragma unroll
    for (int oc = 0; oc < 32; ++oc)
        s4[obase + (size_t)oc * 16 * 16 * 128] = sb[t][oc*2 + pos];
}

// ---------------- L5: sum_pool(s4,2)*88 (delayed) + LIF ----------------
// s4: [8,32,16,16,128] -> s5: [8,32,8,8,128] = [8,2048,128]
__global__ void pool3_lif_k(const float* __restrict__ s4, float* __restrict__ s5) {
    __shared__ float sb[TT][3];
    int t = threadIdx.x & 127, pos = threadIdx.x >> 7;
    int n = blockIdx.x * 2 + pos;
    int px = n & 7, py = (n >> 3) & 7, c = (n >> 6) & 31, b = n >> 11;
    float acc = 0.f;
    if (t > 0) {
        const float* ip = s4 + (size_t)(((b*32 + c)*16 + py*2)*16 + px*2) * 128 + (t - 1);
        acc = (ip[0] + ip[128] + ip[16*128] + ip[17*128]) * POOLW;
    }
    sb[t][pos] = acc;
    __syncthreads();
    if (threadIdx.x < 2) lif_seq_lds(&sb[0][threadIdx.x], 3);
    __syncthreads();
    s5[(size_t)n * TT + t] = sb[t][pos];
}

// ---------------- L6: fc1 tiled K-split GEMM ----------------
// part[kc][b*512+o][t]; block: 64 o x 64 t x 256 K; grid 8kc x 8ot x 2tt x 8b
__global__ __launch_bounds__(256) void fc1_gemm_k(const float* __restrict__ s5,
                                                  const float* __restrict__ wf1,
                                                  float* __restrict__ part) {
    __shared__ float WT[64][68];
    __shared__ float ST[64][68];
    int bid = blockIdx.x;
    int kc = bid & 7;
    int ot = (bid >> 3) & 7;
    int tt = (bid >> 6) & 1;
    int b  = bid >> 7;
    int tid = threadIdx.x;
    int oo = tid >> 4;
    int to = tid & 15;

    const float* wbase = wf1 + (size_t)(ot*64) * 2048 + kc*256;
    const float* sbase = s5 + (size_t)b * 262144 + (size_t)(kc*256) * 128;

    float acc[4][4];
    #pragma unroll
    for (int i = 0; i < 4; ++i)
        #pragma unroll
        for (int j = 0; j < 4; ++j) acc[i][j] = 0.f;

    for (int ks = 0; ks < 4; ++ks) {
        __syncthreads();
        #pragma unroll
        for (int i = 0; i < 16; ++i) {
            int e = tid + 256*i;
            int o = e >> 6, f = e & 63;
            WT[f][o] = wbase[(size_t)o * 2048 + ks*64 + f];
        }
        #pragma unroll
        for (int i = 0; i < 16; ++i) {
            int e = tid + 256*i;
            int f = e >> 6, tl = e & 63;
            int tsrc = tt*64 + tl - 1;
            ST[f][tl] = (tsrc < 0) ? 0.f : sbase[(size_t)f * 128 + ks*64*128 + tsrc];
        }
        __syncthreads();
        #pragma unroll 4
        for (int k = 0; k < 64; ++k) {
            float4 a = *(const float4*)&WT[k][oo*4];
            float4 s = *(const float4*)&ST[k][to*4];
            acc[0][0] = fmaf(a.x, s.x, acc[0][0]);
            acc[0][1] = fmaf(a.x, s.y, acc[0][1]);
            acc[0][2] = fmaf(a.x, s.z, acc[0][2]);
            acc[0][3] = fmaf(a.x, s.w, acc[0][3]);
            acc[1][0] = fmaf(a.y, s.x, acc[1][0]);
            acc[1][1] = fmaf(a.y, s.y, acc[1][1]);
            acc[1][2] = fmaf(a.y, s.z, acc[1][2]);
            acc[1][3] = fmaf(a.y, s.w, acc[1][3]);
            acc[2][0] = fmaf(a.z, s.x, acc[2][0]);
            acc[2][1] = fmaf(a.z, s.y, acc[2][1]);
            acc[2][2] = fmaf(a.z, s.z, acc[2][2]);
            acc[2][3] = fmaf(a.z, s.w, acc[2][3]);
            acc[3][0] = fmaf(a.w, s.x, acc[3][0]);
            acc[3][1] = fmaf(a.w, s.y, acc[3][1]);
            acc[3][2] = fmaf(a.w, s.z, acc[3][2]);
            acc[3][3] = fmaf(a.w, s.w, acc[3][3]);
        }
    }
    float* pb = part + (size_t)kc * 524288 + (size_t)b * 65536
              + (size_t)(ot*64 + oo*4) * 128 + tt*64 + to*4;
    #pragma unroll
    for (int i = 0; i < 4; ++i)
        #pragma unroll
        for (int j = 0; j < 4; ++j)
            pb[(size_t)i * 128 + j] = acc[i][j];
}

// ---------------- L6b: sum 8 K-chunks (fixed order) + LIF -> s6 [8,512,128] ----
__global__ void fc1_reduce_lif_k(const float* __restrict__ part, float* __restrict__ s6) {
    __shared__ float sb[TT][3];
    int t = threadIdx.x & 127, pos = threadIdx.x >> 7;
    int n = blockIdx.x * 2 + pos;
    float s = 0.f;
    #pragma unroll
    for (int kc = 0; kc < 8; ++kc)
        s += part[(size_t)kc * 524288 + (size_t)n * 128 + t];
    sb[t][pos] = s;
    __syncthreads();
    if (threadIdx.x < 2) lif_seq_lds(&sb[0][threadIdx.x], 3);
    __syncthreads();
    s6[(size_t)n * TT + t] = sb[t][pos];
}

// ---------------- L7: fc2 512->11 (delayed) + LIF + final shift -> out ----------
// block per (b,o): 128 threads = t
__global__ void fc2_lif_k(const float* __restrict__ s6, const float* __restrict__ wf2,
                          float* __restrict__ out) {
    __shared__ float sb[TT];
    int t = threadIdx.x;
    int o = blockIdx.x % 11, b = blockIdx.x / 11;
    float acc = 0.f;
    if (t > 0) {
        const float* sp = s6 + (size_t)b * 65536 + (t - 1);
        const float* wp = wf2 + o * 512;
        for (int f = 0; f < 512; f += 4) {
            float4 w = *(const float4*)&wp[f];
            acc = fmaf(w.x, sp[(size_t)f * 128], acc);
            acc = fmaf(w.y, sp[(size_t)(f+1) * 128], acc);
            acc = fmaf(w.z, sp[(size_t)(f+2) * 128], acc);
            acc = fmaf(w.w, sp[(size_t)(f+3) * 128], acc);
        }
    }
    sb[t] = acc;
    __syncthreads();
    if (t == 0) lif_seq_lds(sb, 1);
    __syncthreads();
    float* q = out + (size_t)(b*11 + o) * TT;
    if (t == 0) q[0] = 0.f;
    if (t < TT - 1) q[t + 1] = sb[t];
}

extern "C" void kernel_launch(void* const* d_in, const int* in_sizes, int n_in,
                              void* d_out, int out_size, void* d_ws, size_t ws_size,
                              hipStream_t stream) {
    const float* x   = (const float*)d_in[0];
    const float* w1  = (const float*)d_in[1];
    const float* w2  = (const float*)d_in[2];
    const float* wf1 = (const float*)d_in[3];
    const float* wf2 = (const float*)d_in[4];
    float* out = (float*)d_out;

    float* ws = (float*)d_ws;
    float* A = ws;                       // 4,194,304 floats
    float* B = ws + 4194304;             // 16,777,216 floats
    float* PART = B + 1048576;           // 4,194,304 floats (inside B, after s6)

    // L1: pool1+LIF   (A = s1: [8,2,32,32,128], 16384 neurons)
    pool1_lif_k<<<dim3(8192), 256, 0, stream>>>(x, A);
    // L2: conv1+LIF   (B = s2: [8,16,32,32,128])
    conv1_lif_k<<<dim3(4096), 256, 0, stream>>>(A, w1, B);
    // L3: pool2+LIF   (A = s3: [8,16,16,16,128], 32768 neurons)
    pool2_lif_k<<<dim3(16384), 256, 0, stream>>>(B, A);
    // L4: conv2+LIF   (B = s4: [8,32,16,16,128])
    conv2_lif_k<<<dim3(1024), 256, 0, stream>>>(A, w2, B);
    // L5: pool3+LIF   (A = s5: [8,2048,128], 16384 neurons)
    pool3_lif_k<<<dim3(8192), 256, 0, stream>>>(B, A);
    // L6: fc1 GEMM -> PART; reduce+LIF -> B (s6: [8,512,128], 4096 neurons)
    fc1_gemm_k      <<<dim3(1024), 256, 0, stream>>>(A, wf1, PART);
    fc1_reduce_lif_k<<<dim3(2048), 256, 0, stream>>>(PART, B);
    // L7: fc2+LIF+shift -> d_out
    fc2_lif_k<<<dim3(88), 128, 0, stream>>>(B, wf2, out);
}

// Round 5
// 251.195 us; speedup vs baseline: 3.8131x; 1.1259x over previous
//
#include <hip/hip_runtime.h>

#define TT 128

// LIF constants
#define DECAY_U 0.75f
#define DECAY_V 0.96875f
#define THETA   5120.0f
#define POOLW   88.0f

__device__ __forceinline__ void lif_step(float xt, float& u, float& v, int& refc, float& s) {
    u = __fadd_rn(__fmul_rn(u, DECAY_U), __fmul_rn(xt, 64.0f));
    float vn = __fadd_rn(__fmul_rn(v, DECAY_V), u);
    v = refc ? 0.0f : vn;
    s = (v >= THETA) ? 1.0f : 0.0f;
    if (s > 0.f) { refc = 1; v = 0.f; }
    else         { refc = refc > 0 ? refc - 1 : 0; }
}

// Serial LIF over an LDS column: col[t*stride], t=0..127.
__device__ __forceinline__ void lif_seq_lds(float* col, int stride) {
    float u = 0.f, v = 0.f;
    int refc = 0;
    #pragma unroll 16
    for (int t = 0; t < TT; ++t) {
        float s;
        lif_step(col[t * stride], u, v, refc, s);
        col[t * stride] = s;
    }
}

// Standalone LIF over global rows [n][128], in place, float4.
__global__ void lif_k(float* __restrict__ buf, int N) {
    int n = blockIdx.x * blockDim.x + threadIdx.x;
    if (n >= N) return;
    float4* p = (float4*)(buf + (size_t)n * TT);
    float u = 0.f, v = 0.f;
    int refc = 0;
    #pragma unroll 4
    for (int i = 0; i < TT/4; ++i) {
        float4 x4 = p[i];
        float s0, s1, s2, s3;
        lif_step(x4.x, u, v, refc, s0);
        lif_step(x4.y, u, v, refc, s1);
        lif_step(x4.z, u, v, refc, s2);
        lif_step(x4.w, u, v, refc, s3);
        p[i] = make_float4(s0, s1, s2, s3);
    }
}

// ---------------- L1: sum_pool(x,4)*88 + LIF ----------------
__global__ void pool1_lif_k(const float* __restrict__ x, float* __restrict__ s1) {
    __shared__ float sb[TT][3];
    int t = threadIdx.x & 127, pos = threadIdx.x >> 7;
    int n = blockIdx.x * 2 + pos;
    int px = n & 31, py = (n >> 5) & 31, c = (n >> 10) & 1, b = n >> 11;
    const float* base = x + (size_t)((((b*2 + c)*128 + py*4)*128) + px*4) * 128 + t;
    float s = 0.f;
    #pragma unroll
    for (int dy = 0; dy < 4; ++dy)
        #pragma unroll
        for (int dx = 0; dx < 4; ++dx)
            s += base[(dy*128 + dx) * 128];
    sb[t][pos] = s * POOLW;
    __syncthreads();
    if (threadIdx.x < 2) lif_seq_lds(&sb[0][threadIdx.x], 3);
    __syncthreads();
    s1[(size_t)n * TT + t] = sb[t][pos];
}

// ---------------- L2: conv1 5x5 SAME 2->16 (input delayed) + LIF ----------------
__global__ void conv1_lif_k(const float* __restrict__ s1, const float* __restrict__ w1,
                            float* __restrict__ s2) {
    __shared__ float wT[50][16];
    __shared__ float sb[TT][33];
    // conflict-free staging: LDS address linear in i
    for (int i = threadIdx.x; i < 800; i += 256) {
        int oc = i & 15, ck = i >> 4;
        wT[ck][oc] = w1[oc * 50 + ck];
    }
    __syncthreads();
    int id = blockIdx.x * 256 + threadIdx.x;
    int t = id & 127, pos = threadIdx.x >> 7;
    int n = id >> 7;
    int px = n & 31, py = (n >> 5) & 31, b = n >> 10;
    float acc[16];
    #pragma unroll
    for (int k = 0; k < 16; ++k) acc[k] = 0.f;
    int tsrc = t > 0 ? t - 1 : 0;
    float tm = t > 0 ? 1.f : 0.f;
    const float* sp = s1 + (size_t)(b*2) * 32 * 32 * 128 + tsrc;
    #pragma unroll
    for (int ky = 0; ky < 5; ++ky) {
        int iy = py + ky - 2;
        #pragma unroll
        for (int kx = 0; kx < 5; ++kx) {
            int ix = px + kx - 2;
            bool valid = ((unsigned)iy < 32u) && ((unsigned)ix < 32u);
            float m = valid ? tm : 0.f;
            int iyc = valid ? iy : 0, ixc = valid ? ix : 0;
            const float* ip = sp + (iyc*32 + ixc) * 128;
            float xv[2];
            xv[0] = ip[0];
            xv[1] = ip[32*32*128];
            #pragma unroll
            for (int c = 0; c < 2; ++c) {
                float xm = xv[c] * m;
                const float4* wv = (const float4*)wT[c*25 + ky*5 + kx];
                #pragma unroll
                for (int j = 0; j < 4; ++j) {
                    float4 w = wv[j];
                    acc[j*4+0] = fmaf(w.x, xm, acc[j*4+0]);
                    acc[j*4+1] = fmaf(w.y, xm, acc[j*4+1]);
                    acc[j*4+2] = fmaf(w.z, xm, acc[j*4+2]);
                    acc[j*4+3] = fmaf(w.w, xm, acc[j*4+3]);
                }
            }
        }
    }
    #pragma unroll
    for (int oc = 0; oc < 16; ++oc) sb[t][oc*2 + pos] = acc[oc];
    __syncthreads();
    if (threadIdx.x < 32) lif_seq_lds(&sb[0][threadIdx.x], 33);
    __syncthreads();
    size_t obase = (((size_t)(b*16) * 32 + py) * 32 + px) * 128 + t;
    #pragma unroll
    for (int oc = 0; oc < 16; ++oc)
        s2[obase + (size_t)oc * 32 * 32 * 128] = sb[t][oc*2 + pos];
}

// ---------------- L3: sum_pool(s2,2)*88 (delayed) + LIF ----------------
__global__ void pool2_lif_k(const float* __restrict__ s2, float* __restrict__ s3) {
    __shared__ float sb[TT][3];
    int t = threadIdx.x & 127, pos = threadIdx.x >> 7;
    int n = blockIdx.x * 2 + pos;
    int px = n & 15, py = (n >> 4) & 15, c = (n >> 8) & 15, b = n >> 12;
    float acc = 0.f;
    if (t > 0) {
        const float* ip = s2 + (size_t)(((b*16 + c)*32 + py*2)*32 + px*2) * 128 + (t - 1);
        acc = (ip[0] + ip[128] + ip[32*128] + ip[33*128]) * POOLW;
    }
    sb[t][pos] = acc;
    __syncthreads();
    if (threadIdx.x < 2) lif_seq_lds(&sb[0][threadIdx.x], 3);
    __syncthreads();
    s3[(size_t)n * TT + t] = sb[t][pos];
}

// ---------------- L4 drive: conv2 3x3 SAME 16->32 (delayed), unfused ----------------
// s3: [8,16,16,16,128] -> d4: [8,32,16,16,128]; masked unconditional loads
__global__ __launch_bounds__(256) void conv2_k(const float* __restrict__ s3,
                                               const float* __restrict__ w2,
                                               float* __restrict__ d4) {
    __shared__ float wT[144][32];
    // conflict-free staging: LDS address linear in i
    for (int i = threadIdx.x; i < 4608; i += 256) {
        int oc = i & 31, ck = i >> 5;
        wT[ck][oc] = w2[oc * 144 + ck];
    }
    __syncthreads();
    int id = blockIdx.x * 256 + threadIdx.x;
    int t = id & 127;
    int n = id >> 7;
    int px = n & 15, py = (n >> 4) & 15, b = n >> 8;
    float acc[32];
    #pragma unroll
    for (int k = 0; k < 32; ++k) acc[k] = 0.f;
    int tsrc = t > 0 ? t - 1 : 0;
    float tm = t > 0 ? 1.f : 0.f;
    const float* sp = s3 + (size_t)(b*16) * 16 * 16 * 128 + tsrc;
    #pragma unroll
    for (int ky = 0; ky < 3; ++ky) {
        int iy = py + ky - 1;
        #pragma unroll
        for (int kx = 0; kx < 3; ++kx) {
            int ix = px + kx - 1;
            bool valid = ((unsigned)iy < 16u) && ((unsigned)ix < 16u);
            float m = valid ? tm : 0.f;
            int iyc = valid ? iy : 0, ixc = valid ? ix : 0;
            const float* ip = sp + (iyc*16 + ixc) * 128;
            float xv[16];
            #pragma unroll
            for (int c = 0; c < 16; ++c)
                xv[c] = ip[(size_t)c * 32768];
            #pragma unroll
            for (int c = 0; c < 16; ++c) {
                float xm = xv[c] * m;
                const float4* wv = (const float4*)wT[c*9 + ky*3 + kx];
                #pragma unroll
                for (int j = 0; j < 8; ++j) {
                    float4 w = wv[j];
                    acc[j*4+0] = fmaf(w.x, xm, acc[j*4+0]);
                    acc[j*4+1] = fmaf(w.y, xm, acc[j*4+1]);
                    acc[j*4+2] = fmaf(w.z, xm, acc[j*4+2]);
                    acc[j*4+3] = fmaf(w.w, xm, acc[j*4+3]);
                }
            }
        }
    }
    size_t obase = (((size_t)(b*32) * 16 + py) * 16 + px) * 128 + t;
    #pragma unroll
    for (int oc = 0; oc < 32; ++oc)
        d4[obase + (size_t)oc * 32768] = acc[oc];
}

// ---------------- L5: sum_pool(s4,2)*88 (delayed) + LIF ----------------
__global__ void pool3_lif_k(const float* __restrict__ s4, float* __restrict__ s5) {
    __shared__ float sb[TT][3];
    int t = threadIdx.x & 127, pos = threadIdx.x >> 7;
    int n = blockIdx.x * 2 + pos;
    int px = n & 7, py = (n >> 3) & 7, c = (n >> 6) & 31, b = n >> 11;
    float acc = 0.f;
    if (t > 0) {
        const float* ip = s4 + (size_t)(((b*32 + c)*16 + py*2)*16 + px*2) * 128 + (t - 1);
        acc = (ip[0] + ip[128] + ip[16*128] + ip[17*128]) * POOLW;
    }
    sb[t][pos] = acc;
    __syncthreads();
    if (threadIdx.x < 2) lif_seq_lds(&sb[0][threadIdx.x], 3);
    __syncthreads();
    s5[(size_t)n * TT + t] = sb[t][pos];
}

// ---------------- L6: fc1 tiled K-split GEMM ----------------
__global__ __launch_bounds__(256) void fc1_gemm_k(const float* __restrict__ s5,
                                                  const float* __restrict__ wf1,
                                                  float* __restrict__ part) {
    __shared__ float WT[64][68];
    __shared__ float ST[64][68];
    int bid = blockIdx.x;
    int kc = bid & 7;
    int ot = (bid >> 3) & 7;
    int tt = (bid >> 6) & 1;
    int b  = bid >> 7;
    int tid = threadIdx.x;
    int oo = tid >> 4;
    int to = tid & 15;

    const float* wbase = wf1 + (size_t)(ot*64) * 2048 + kc*256;
    const float* sbase = s5 + (size_t)b * 262144 + (size_t)(kc*256) * 128;

    float acc[4][4];
    #pragma unroll
    for (int i = 0; i < 4; ++i)
        #pragma unroll
        for (int j = 0; j < 4; ++j) acc[i][j] = 0.f;

    for (int ks = 0; ks < 4; ++ks) {
        __syncthreads();
        #pragma unroll
        for (int i = 0; i < 16; ++i) {
            int e = tid + 256*i;
            int o = e >> 6, f = e & 63;
            WT[f][o] = wbase[(size_t)o * 2048 + ks*64 + f];
        }
        #pragma unroll
        for (int i = 0; i < 16; ++i) {
            int e = tid + 256*i;
            int f = e >> 6, tl = e & 63;
            int tsrc = tt*64 + tl - 1;
            ST[f][tl] = (tsrc < 0) ? 0.f : sbase[(size_t)f * 128 + ks*64*128 + tsrc];
        }
        __syncthreads();
        #pragma unroll 4
        for (int k = 0; k < 64; ++k) {
            float4 a = *(const float4*)&WT[k][oo*4];
            float4 s = *(const float4*)&ST[k][to*4];
            acc[0][0] = fmaf(a.x, s.x, acc[0][0]);
            acc[0][1] = fmaf(a.x, s.y, acc[0][1]);
            acc[0][2] = fmaf(a.x, s.z, acc[0][2]);
            acc[0][3] = fmaf(a.x, s.w, acc[0][3]);
            acc[1][0] = fmaf(a.y, s.x, acc[1][0]);
            acc[1][1] = fmaf(a.y, s.y, acc[1][1]);
            acc[1][2] = fmaf(a.y, s.z, acc[1][2]);
            acc[1][3] = fmaf(a.y, s.w, acc[1][3]);
            acc[2][0] = fmaf(a.z, s.x, acc[2][0]);
            acc[2][1] = fmaf(a.z, s.y, acc[2][1]);
            acc[2][2] = fmaf(a.z, s.z, acc[2][2]);
            acc[2][3] = fmaf(a.z, s.w, acc[2][3]);
            acc[3][0] = fmaf(a.w, s.x, acc[3][0]);
            acc[3][1] = fmaf(a.w, s.y, acc[3][1]);
            acc[3][2] = fmaf(a.w, s.z, acc[3][2]);
            acc[3][3] = fmaf(a.w, s.w, acc[3][3]);
        }
    }
    float* pb = part + (size_t)kc * 524288 + (size_t)b * 65536
              + (size_t)(ot*64 + oo*4) * 128 + tt*64 + to*4;
    #pragma unroll
    for (int i = 0; i < 4; ++i)
        #pragma unroll
        for (int j = 0; j < 4; ++j)
            pb[(size_t)i * 128 + j] = acc[i][j];
}

// ---------------- L6b: sum 8 K-chunks (fixed order) + LIF -> s6 ----------------
__global__ void fc1_reduce_lif_k(const float* __restrict__ part, float* __restrict__ s6) {
    __shared__ float sb[TT][3];
    int t = threadIdx.x & 127, pos = threadIdx.x >> 7;
    int n = blockIdx.x * 2 + pos;
    float s = 0.f;
    #pragma unroll
    for (int kc = 0; kc < 8; ++kc)
        s += part[(size_t)kc * 524288 + (size_t)n * 128 + t];
    sb[t][pos] = s;
    __syncthreads();
    if (threadIdx.x < 2) lif_seq_lds(&sb[0][threadIdx.x], 3);
    __syncthreads();
    s6[(size_t)n * TT + t] = sb[t][pos];
}

// ---------------- L7: fc2 512->11 (delayed) + LIF + final shift -> out ----------
__global__ void fc2_lif_k(const float* __restrict__ s6, const float* __restrict__ wf2,
                          float* __restrict__ out) {
    __shared__ float sb[TT];
    int t = threadIdx.x;
    int o = blockIdx.x % 11, b = blockIdx.x / 11;
    float acc = 0.f;
    if (t > 0) {
        const float* sp = s6 + (size_t)b * 65536 + (t - 1);
        const float* wp = wf2 + o * 512;
        for (int f = 0; f < 512; f += 4) {
            float4 w = *(const float4*)&wp[f];
            acc = fmaf(w.x, sp[(size_t)f * 128], acc);
            acc = fmaf(w.y, sp[(size_t)(f+1) * 128], acc);
            acc = fmaf(w.z, sp[(size_t)(f+2) * 128], acc);
            acc = fmaf(w.w, sp[(size_t)(f+3) * 128], acc);
        }
    }
    sb[t] = acc;
    __syncthreads();
    if (t == 0) lif_seq_lds(sb, 1);
    __syncthreads();
    float* q = out + (size_t)(b*11 + o) * TT;
    if (t == 0) q[0] = 0.f;
    if (t < TT - 1) q[t + 1] = sb[t];
}

extern "C" void kernel_launch(void* const* d_in, const int* in_sizes, int n_in,
                              void* d_out, int out_size, void* d_ws, size_t ws_size,
                              hipStream_t stream) {
    const float* x   = (const float*)d_in[0];
    const float* w1  = (const float*)d_in[1];
    const float* w2  = (const float*)d_in[2];
    const float* wf1 = (const float*)d_in[3];
    const float* wf2 = (const float*)d_in[4];
    float* out = (float*)d_out;

    float* ws = (float*)d_ws;
    float* A    = ws;                        // 4,194,304 floats (s1/s3/s5)
    float* B    = ws + 4194304;              // 16,777,216 floats (s2; later s6)
    float* PART = B + 1048576;               // 4,194,304 floats
    float* D4   = ws + 4194304 + 16777216;   // 8,388,608 floats (conv2 drive -> s4)

    // L1: pool1+LIF   (A = s1)
    pool1_lif_k<<<dim3(8192), 256, 0, stream>>>(x, A);
    // L2: conv1+LIF   (B = s2)
    conv1_lif_k<<<dim3(4096), 256, 0, stream>>>(A, w1, B);
    // L3: pool2+LIF   (A = s3)
    pool2_lif_k<<<dim3(16384), 256, 0, stream>>>(B, A);
    // L4: conv2 drive -> D4, then LIF in place (D4 = s4)
    conv2_k<<<dim3(1024), 256, 0, stream>>>(A, w2, D4);
    lif_k  <<<dim3(256),  256, 0, stream>>>(D4, 65536);
    // L5: pool3+LIF   (A = s5)
    pool3_lif_k<<<dim3(8192), 256, 0, stream>>>(D4, A);
    // L6: fc1 GEMM -> PART; reduce+LIF -> B (s6)
    fc1_gemm_k      <<<dim3(1024), 256, 0, stream>>>(A, wf1, PART);
    fc1_reduce_lif_k<<<dim3(2048), 256, 0, stream>>>(PART, B);
    // L7: fc2+LIF+shift -> d_out
    fc2_lif_k<<<dim3(88), 128, 0, stream>>>(B, wf2, out);
}

// Round 6
// 249.242 us; speedup vs baseline: 3.8430x; 1.0078x over previous
//
#include <hip/hip_runtime.h>

#define TT 128

// LIF constants
#define DECAY_U 0.75f
#define DECAY_V 0.96875f
#define THETA   5120.0f
#define POOLW   88.0f

__device__ __forceinline__ void lif_step(float xt, float& u, float& v, int& refc, float& s) {
    u = __fadd_rn(__fmul_rn(u, DECAY_U), __fmul_rn(xt, 64.0f));
    float vn = __fadd_rn(__fmul_rn(v, DECAY_V), u);
    v = refc ? 0.0f : vn;
    s = (v >= THETA) ? 1.0f : 0.0f;
    if (s > 0.f) { refc = 1; v = 0.f; }
    else         { refc = refc > 0 ? refc - 1 : 0; }
}

// Serial LIF over an LDS column: col[t*stride], t=0..127.
__device__ __forceinline__ void lif_seq_lds(float* col, int stride) {
    float u = 0.f, v = 0.f;
    int refc = 0;
    #pragma unroll 16
    for (int t = 0; t < TT; ++t) {
        float s;
        lif_step(col[t * stride], u, v, refc, s);
        col[t * stride] = s;
    }
}

// ---------------- Weight transpose: [oc][ck] -> [ck][oc] (oc contiguous) ----------
__global__ void wtrans_k(const float* __restrict__ w1, const float* __restrict__ w2,
                         float* __restrict__ wTg1, float* __restrict__ wTg2) {
    int i = blockIdx.x * 256 + threadIdx.x;
    if (i < 800) {
        int oc = i & 15, ck = i >> 4;          // ck = c*25 + ky*5 + kx
        wTg1[ck*16 + oc] = w1[oc*50 + ck];
    }
    if (i < 4608) {
        int oc = i & 31, ck = i >> 5;          // ck = c*9 + ky*3 + kx
        wTg2[ck*32 + oc] = w2[oc*144 + ck];
    }
}

// ---------------- L1: sum_pool(x,4)*88 + LIF ----------------
__global__ void pool1_lif_k(const float* __restrict__ x, float* __restrict__ s1) {
    __shared__ float sb[TT][3];
    int t = threadIdx.x & 127, pos = threadIdx.x >> 7;
    int n = blockIdx.x * 2 + pos;
    int px = n & 31, py = (n >> 5) & 31, c = (n >> 10) & 1, b = n >> 11;
    const float* base = x + (size_t)((((b*2 + c)*128 + py*4)*128) + px*4) * 128 + t;
    float s = 0.f;
    #pragma unroll
    for (int dy = 0; dy < 4; ++dy)
        #pragma unroll
        for (int dx = 0; dx < 4; ++dx)
            s += base[(dy*128 + dx) * 128];
    sb[t][pos] = s * POOLW;
    __syncthreads();
    if (threadIdx.x < 2) lif_seq_lds(&sb[0][threadIdx.x], 3);
    __syncthreads();
    s1[(size_t)n * TT + t] = sb[t][pos];
}

// ---------------- L2: conv1 5x5 SAME 2->16 (input delayed) + LIF ----------------
// Weights via wave-uniform global reads (SGPR path), no weight LDS.
__global__ __launch_bounds__(256) void conv1_lif_k(const float* __restrict__ s1,
                                                   const float* __restrict__ wTg1,
                                                   float* __restrict__ s2) {
    __shared__ float sb[TT][33];
    int id = blockIdx.x * 256 + threadIdx.x;
    int t = id & 127, pos = threadIdx.x >> 7;
    int n = id >> 7;
    int px = n & 31, py = (n >> 5) & 31, b = n >> 10;
    float acc[16];
    #pragma unroll
    for (int k = 0; k < 16; ++k) acc[k] = 0.f;
    int tsrc = t > 0 ? t - 1 : 0;
    float tm = t > 0 ? 1.f : 0.f;
    const float* sp = s1 + (size_t)(b*2) * 32 * 32 * 128 + tsrc;
    #pragma unroll
    for (int ky = 0; ky < 5; ++ky) {
        int iy = py + ky - 2;
        #pragma unroll
        for (int kx = 0; kx < 5; ++kx) {
            int ix = px + kx - 2;
            bool valid = ((unsigned)iy < 32u) && ((unsigned)ix < 32u);
            float m = valid ? tm : 0.f;
            int iyc = valid ? iy : 0, ixc = valid ? ix : 0;
            const float* ip = sp + (iyc*32 + ixc) * 128;
            float xv0 = ip[0] * m;
            float xv1 = ip[32*32*128] * m;
            #pragma unroll
            for (int c = 0; c < 2; ++c) {
                float xm = c ? xv1 : xv0;
                const float4* wv = (const float4*)&wTg1[(c*25 + ky*5 + kx) * 16];
                #pragma unroll
                for (int j = 0; j < 4; ++j) {
                    float4 w = wv[j];
                    acc[j*4+0] = fmaf(w.x, xm, acc[j*4+0]);
                    acc[j*4+1] = fmaf(w.y, xm, acc[j*4+1]);
                    acc[j*4+2] = fmaf(w.z, xm, acc[j*4+2]);
                    acc[j*4+3] = fmaf(w.w, xm, acc[j*4+3]);
                }
            }
        }
    }
    #pragma unroll
    for (int oc = 0; oc < 16; ++oc) sb[t][oc*2 + pos] = acc[oc];
    __syncthreads();
    if (threadIdx.x < 32) lif_seq_lds(&sb[0][threadIdx.x], 33);
    __syncthreads();
    size_t obase = (((size_t)(b*16) * 32 + py) * 32 + px) * 128 + t;
    #pragma unroll
    for (int oc = 0; oc < 16; ++oc)
        s2[obase + (size_t)oc * 32 * 32 * 128] = sb[t][oc*2 + pos];
}

// ---------------- L3: sum_pool(s2,2)*88 (delayed) + LIF ----------------
__global__ void pool2_lif_k(const float* __restrict__ s2, float* __restrict__ s3) {
    __shared__ float sb[TT][3];
    int t = threadIdx.x & 127, pos = threadIdx.x >> 7;
    int n = blockIdx.x * 2 + pos;
    int px = n & 15, py = (n >> 4) & 15, c = (n >> 8) & 15, b = n >> 12;
    float acc = 0.f;
    if (t > 0) {
        const float* ip = s2 + (size_t)(((b*16 + c)*32 + py*2)*32 + px*2) * 128 + (t - 1);
        acc = (ip[0] + ip[128] + ip[32*128] + ip[33*128]) * POOLW;
    }
    sb[t][pos] = acc;
    __syncthreads();
    if (threadIdx.x < 2) lif_seq_lds(&sb[0][threadIdx.x], 3);
    __syncthreads();
    s3[(size_t)n * TT + t] = sb[t][pos];
}

// ---------------- L4: conv2 3x3 SAME 16->32 (delayed) + LIF ----------------
// Weights via wave-uniform global reads (SGPR path), no weight LDS.
__global__ __launch_bounds__(256) void conv2_lif_k(const float* __restrict__ s3,
                                                   const float* __restrict__ wTg2,
                                                   float* __restrict__ s4) {
    __shared__ float sb[TT][65];
    int id = blockIdx.x * 256 + threadIdx.x;
    int t = id & 127, pos = threadIdx.x >> 7;
    int n = id >> 7;
    int px = n & 15, py = (n >> 4) & 15, b = n >> 8;
    float acc[32];
    #pragma unroll
    for (int k = 0; k < 32; ++k) acc[k] = 0.f;
    int tsrc = t > 0 ? t - 1 : 0;
    float tm = t > 0 ? 1.f : 0.f;
    const float* sp = s3 + (size_t)(b*16) * 16 * 16 * 128 + tsrc;
    #pragma unroll
    for (int ky = 0; ky < 3; ++ky) {
        int iy = py + ky - 1;
        #pragma unroll
        for (int kx = 0; kx < 3; ++kx) {
            int ix = px + kx - 1;
            bool valid = ((unsigned)iy < 16u) && ((unsigned)ix < 16u);
            float m = valid ? tm : 0.f;
            int iyc = valid ? iy : 0, ixc = valid ? ix : 0;
            const float* ip = sp + (iyc*16 + ixc) * 128;
            float xv[16];
            #pragma unroll
            for (int c = 0; c < 16; ++c)
                xv[c] = ip[(size_t)c * 32768];
            #pragma unroll
            for (int c = 0; c < 16; ++c) {
                float xm = xv[c] * m;
                const float4* wv = (const float4*)&wTg2[(c*9 + ky*3 + kx) * 32];
                #pragma unroll
                for (int j = 0; j < 8; ++j) {
                    float4 w = wv[j];
                    acc[j*4+0] = fmaf(w.x, xm, acc[j*4+0]);
                    acc[j*4+1] = fmaf(w.y, xm, acc[j*4+1]);
                    acc[j*4+2] = fmaf(w.z, xm, acc[j*4+2]);
                    acc[j*4+3] = fmaf(w.w, xm, acc[j*4+3]);
                }
            }
        }
    }
    #pragma unroll
    for (int oc = 0; oc < 32; ++oc) sb[t][oc*2 + pos] = acc[oc];
    __syncthreads();
    if (threadIdx.x < 64) lif_seq_lds(&sb[0][threadIdx.x], 65);
    __syncthreads();
    size_t obase = (((size_t)(b*32) * 16 + py) * 16 + px) * 128 + t;
    #pragma unroll
    for (int oc = 0; oc < 32; ++oc)
        s4[obase + (size_t)oc * 32768] = sb[t][oc*2 + pos];
}

// ---------------- L5: sum_pool(s4,2)*88 (delayed) + LIF ----------------
__global__ void pool3_lif_k(const float* __restrict__ s4, float* __restrict__ s5) {
    __shared__ float sb[TT][3];
    int t = threadIdx.x & 127, pos = threadIdx.x >> 7;
    int n = blockIdx.x * 2 + pos;
    int px = n & 7, py = (n >> 3) & 7, c = (n >> 6) & 31, b = n >> 11;
    float acc = 0.f;
    if (t > 0) {
        const float* ip = s4 + (size_t)(((b*32 + c)*16 + py*2)*16 + px*2) * 128 + (t - 1);
        acc = (ip[0] + ip[128] + ip[16*128] + ip[17*128]) * POOLW;
    }
    sb[t][pos] = acc;
    __syncthreads();
    if (threadIdx.x < 2) lif_seq_lds(&sb[0][threadIdx.x], 3);
    __syncthreads();
    s5[(size_t)n * TT + t] = sb[t][pos];
}

// ---------------- L6: fc1 tiled K-split GEMM ----------------
__global__ __launch_bounds__(256) void fc1_gemm_k(const float* __restrict__ s5,
                                                  const float* __restrict__ wf1,
                                                  float* __restrict__ part) {
    __shared__ float WT[64][68];
    __shared__ float ST[64][68];
    int bid = blockIdx.x;
    int kc = bid & 7;
    int ot = (bid >> 3) & 7;
    int tt = (bid >> 6) & 1;
    int b  = bid >> 7;
    int tid = threadIdx.x;
    int oo = tid >> 4;
    int to = tid & 15;

    const float* wbase = wf1 + (size_t)(ot*64) * 2048 + kc*256;
    const float* sbase = s5 + (size_t)b * 262144 + (size_t)(kc*256) * 128;

    float acc[4][4];
    #pragma unroll
    for (int i = 0; i < 4; ++i)
        #pragma unroll
        for (int j = 0; j < 4; ++j) acc[i][j] = 0.f;

    for (int ks = 0; ks < 4; ++ks) {
        __syncthreads();
        #pragma unroll
        for (int i = 0; i < 16; ++i) {
            int e = tid + 256*i;
            int o = e >> 6, f = e & 63;
            WT[f][o] = wbase[(size_t)o * 2048 + ks*64 + f];
        }
        #pragma unroll
        for (int i = 0; i < 16; ++i) {
            int e = tid + 256*i;
            int f = e >> 6, tl = e & 63;
            int tsrc = tt*64 + tl - 1;
            ST[f][tl] = (tsrc < 0) ? 0.f : sbase[(size_t)f * 128 + ks*64*128 + tsrc];
        }
        __syncthreads();
        #pragma unroll 4
        for (int k = 0; k < 64; ++k) {
            float4 a = *(const float4*)&WT[k][oo*4];
            float4 s = *(const float4*)&ST[k][to*4];
            acc[0][0] = fmaf(a.x, s.x, acc[0][0]);
            acc[0][1] = fmaf(a.x, s.y, acc[0][1]);
            acc[0][2] = fmaf(a.x, s.z, acc[0][2]);
            acc[0][3] = fmaf(a.x, s.w, acc[0][3]);
            acc[1][0] = fmaf(a.y, s.x, acc[1][0]);
            acc[1][1] = fmaf(a.y, s.y, acc[1][1]);
            acc[1][2] = fmaf(a.y, s.z, acc[1][2]);
            acc[1][3] = fmaf(a.y, s.w, acc[1][3]);
            acc[2][0] = fmaf(a.z, s.x, acc[2][0]);
            acc[2][1] = fmaf(a.z, s.y, acc[2][1]);
            acc[2][2] = fmaf(a.z, s.z, acc[2][2]);
            acc[2][3] = fmaf(a.z, s.w, acc[2][3]);
            acc[3][0] = fmaf(a.w, s.x, acc[3][0]);
            acc[3][1] = fmaf(a.w, s.y, acc[3][1]);
            acc[3][2] = fmaf(a.w, s.z, acc[3][2]);
            acc[3][3] = fmaf(a.w, s.w, acc[3][3]);
        }
    }
    float* pb = part + (size_t)kc * 524288 + (size_t)b * 65536
              + (size_t)(ot*64 + oo*4) * 128 + tt*64 + to*4;
    #pragma unroll
    for (int i = 0; i < 4; ++i)
        #pragma unroll
        for (int j = 0; j < 4; ++j)
            pb[(size_t)i * 128 + j] = acc[i][j];
}

// ---------------- L6b: sum 8 K-chunks (fixed order) + LIF -> s6 ----------------
__global__ void fc1_reduce_lif_k(const float* __restrict__ part, float* __restrict__ s6) {
    __shared__ float sb[TT][3];
    int t = threadIdx.x & 127, pos = threadIdx.x >> 7;
    int n = blockIdx.x * 2 + pos;
    float s = 0.f;
    #pragma unroll
    for (int kc = 0; kc < 8; ++kc)
        s += part[(size_t)kc * 524288 + (size_t)n * 128 + t];
    sb[t][pos] = s;
    __syncthreads();
    if (threadIdx.x < 2) lif_seq_lds(&sb[0][threadIdx.x], 3);
    __syncthreads();
    s6[(size_t)n * TT + t] = sb[t][pos];
}

// ---------------- L7: fc2 512->11 (delayed) + LIF + final shift -> out ----------
__global__ void fc2_lif_k(const float* __restrict__ s6, const float* __restrict__ wf2,
                          float* __restrict__ out) {
    __shared__ float sb[TT];
    int t = threadIdx.x;
    int o = blockIdx.x % 11, b = blockIdx.x / 11;
    float acc = 0.f;
    if (t > 0) {
        const float* sp = s6 + (size_t)b * 65536 + (t - 1);
        const float* wp = wf2 + o * 512;
        for (int f = 0; f < 512; f += 4) {
            float4 w = *(const float4*)&wp[f];
            acc = fmaf(w.x, sp[(size_t)f * 128], acc);
            acc = fmaf(w.y, sp[(size_t)(f+1) * 128], acc);
            acc = fmaf(w.z, sp[(size_t)(f+2) * 128], acc);
            acc = fmaf(w.w, sp[(size_t)(f+3) * 128], acc);
        }
    }
    sb[t] = acc;
    __syncthreads();
    if (t == 0) lif_seq_lds(sb, 1);
    __syncthreads();
    float* q = out + (size_t)(b*11 + o) * TT;
    if (t == 0) q[0] = 0.f;
    if (t < TT - 1) q[t + 1] = sb[t];
}

extern "C" void kernel_launch(void* const* d_in, const int* in_sizes, int n_in,
                              void* d_out, int out_size, void* d_ws, size_t ws_size,
                              hipStream_t stream) {
    const float* x   = (const float*)d_in[0];
    const float* w1  = (const float*)d_in[1];
    const float* w2  = (const float*)d_in[2];
    const float* wf1 = (const float*)d_in[3];
    const float* wf2 = (const float*)d_in[4];
    float* out = (float*)d_out;

    float* ws = (float*)d_ws;
    float* A    = ws;                        // 4,194,304 floats (s1/s3/s5)
    float* B    = ws + 4194304;              // 16,777,216 floats (s2; later s6)
    float* PART = B + 1048576;               // 4,194,304 floats
    float* D4   = ws + 4194304 + 16777216;   // 8,388,608 floats (s4)
    float* WT1  = D4 + 8388608;              // 800 floats
    float* WT2  = WT1 + 800;                 // 4608 floats

    // W transpose (oc contiguous) for the SGPR weight path
    wtrans_k<<<dim3(18), 256, 0, stream>>>(w1, w2, WT1, WT2);
    // L1: pool1+LIF   (A = s1)
    pool1_lif_k<<<dim3(8192), 256, 0, stream>>>(x, A);
    // L2: conv1+LIF   (B = s2)
    conv1_lif_k<<<dim3(4096), 256, 0, stream>>>(A, WT1, B);
    // L3: pool2+LIF   (A = s3)
    pool2_lif_k<<<dim3(16384), 256, 0, stream>>>(B, A);
    // L4: conv2+LIF   (D4 = s4)
    conv2_lif_k<<<dim3(1024), 256, 0, stream>>>(A, WT2, D4);
    // L5: pool3+LIF   (A = s5)
    pool3_lif_k<<<dim3(8192), 256, 0, stream>>>(D4, A);
    // L6: fc1 GEMM -> PART; reduce+LIF -> B (s6)
    fc1_gemm_k      <<<dim3(1024), 256, 0, stream>>>(A, wf1, PART);
    fc1_reduce_lif_k<<<dim3(2048), 256, 0, stream>>>(PART, B);
    // L7: fc2+LIF+shift -> d_out
    fc2_lif_k<<<dim3(88), 128, 0, stream>>>(B, wf2, out);
}

// Round 7
// 248.595 us; speedup vs baseline: 3.8530x; 1.0026x over previous
//
#include <hip/hip_runtime.h>

#define TT 128

// LIF constants
#define DECAY_U 0.75f
#define DECAY_V 0.96875f
#define THETA   5120.0f
#define POOLW   88.0f

__device__ __forceinline__ void lif_step(float xt, float& u, float& v, int& refc, float& s) {
    u = __fadd_rn(__fmul_rn(u, DECAY_U), __fmul_rn(xt, 64.0f));
    float vn = __fadd_rn(__fmul_rn(v, DECAY_V), u);
    v = refc ? 0.0f : vn;
    s = (v >= THETA) ? 1.0f : 0.0f;
    if (s > 0.f) { refc = 1; v = 0.f; }
    else         { refc = refc > 0 ? refc - 1 : 0; }
}

// Serial LIF over an LDS column: col[t*stride], t=0..127.
__device__ __forceinline__ void lif_seq_lds(float* col, int stride) {
    float u = 0.f, v = 0.f;
    int refc = 0;
    #pragma unroll 16
    for (int t = 0; t < TT; ++t) {
        float s;
        lif_step(col[t * stride], u, v, refc, s);
        col[t * stride] = s;
    }
}

// ---------------- Weight transpose: [oc][ck] -> [ck][oc] (oc contiguous) ----------
__global__ void wtrans_k(const float* __restrict__ w1, const float* __restrict__ w2,
                         float* __restrict__ wTg1, float* __restrict__ wTg2) {
    int i = blockIdx.x * 256 + threadIdx.x;
    if (i < 800) {
        int oc = i & 15, ck = i >> 4;          // ck = c*25 + tap
        wTg1[ck*16 + oc] = w1[oc*50 + ck];
    }
    if (i < 4608) {
        int oc = i & 31, ck = i >> 5;          // ck = c*9 + tap
        wTg2[ck*32 + oc] = w2[oc*144 + ck];
    }
}

// ---------------- L1: sum_pool(x,4)*88 + LIF ----------------
__global__ void pool1_lif_k(const float* __restrict__ x, float* __restrict__ s1) {
    __shared__ float sb[TT][3];
    int t = threadIdx.x & 127, pos = threadIdx.x >> 7;
    int n = blockIdx.x * 2 + pos;
    int px = n & 31, py = (n >> 5) & 31, c = (n >> 10) & 1, b = n >> 11;
    const float* base = x + (size_t)((((b*2 + c)*128 + py*4)*128) + px*4) * 128 + t;
    float s = 0.f;
    #pragma unroll
    for (int dy = 0; dy < 4; ++dy)
        #pragma unroll
        for (int dx = 0; dx < 4; ++dx)
            s += base[(dy*128 + dx) * 128];
    sb[t][pos] = s * POOLW;
    __syncthreads();
    if (threadIdx.x < 2) lif_seq_lds(&sb[0][threadIdx.x], 3);
    __syncthreads();
    s1[(size_t)n * TT + t] = sb[t][pos];
}

// ---------------- pack s1 (2 c bits) -> pk1 [8][32][32][128] uint8 ----------------
__global__ void pack1_k(const float* __restrict__ s1, unsigned char* __restrict__ pk1) {
    int id = blockIdx.x * 256 + threadIdx.x;     // 1,048,576
    int t = id & 127;
    int pos = id >> 7;                            // b*1024 + py*32+px
    int b = pos >> 10, rem = pos & 1023;
    const float* p0 = s1 + (size_t)(b*2) * 131072 + rem * 128 + t;
    unsigned int v = (p0[0] > 0.5f ? 1u : 0u) | (p0[131072] > 0.5f ? 2u : 0u);
    pk1[id] = (unsigned char)v;
}

// ---------------- pack s3 (16 c bits) -> pk3 [8][16][16][128] uint16 ----------------
__global__ void pack2_k(const float* __restrict__ s3, unsigned short* __restrict__ pk3) {
    int id = blockIdx.x * 256 + threadIdx.x;     // 262,144
    int t = id & 127;
    int pos = id >> 7;                            // b*256 + py*16+px
    int b = pos >> 8, rem = pos & 255;
    const float* p0 = s3 + (size_t)(b*16) * 32768 + rem * 128 + t;
    unsigned int v = 0;
    #pragma unroll
    for (int c = 0; c < 16; ++c)
        v |= (p0[(size_t)c * 32768] > 0.5f ? 1u : 0u) << c;
    pk3[id] = (unsigned short)v;
}

// ---------------- L2: conv1 5x5 SAME 2->16 (delayed, bit-packed input) + LIF ------
__global__ __launch_bounds__(256) void conv1_lif_k(const unsigned char* __restrict__ pk1,
                                                   const float* __restrict__ wTg1,
                                                   float* __restrict__ s2) {
    __shared__ float sb[TT][33];
    int id = blockIdx.x * 256 + threadIdx.x;
    int t = id & 127, pos = threadIdx.x >> 7;
    int n = id >> 7;
    int px = n & 31, py = (n >> 5) & 31, b = n >> 10;
    int tsrc = t > 0 ? t - 1 : 0;
    const unsigned char* pp = pk1 + (size_t)b * 131072 + tsrc;
    // all 25 tap loads upfront
    unsigned int pkv[25];
    #pragma unroll
    for (int ky = 0; ky < 5; ++ky) {
        int iy = py + ky - 2;
        #pragma unroll
        for (int kx = 0; kx < 5; ++kx) {
            int ix = px + kx - 2;
            bool valid = ((unsigned)iy < 32u) && ((unsigned)ix < 32u) && (t > 0);
            int iyc = valid ? iy : 0, ixc = valid ? ix : 0;
            unsigned int v = pp[(iyc*32 + ixc) * 128];
            pkv[ky*5 + kx] = valid ? v : 0u;
        }
    }
    float acc[16];
    #pragma unroll
    for (int k = 0; k < 16; ++k) acc[k] = 0.f;
    #pragma unroll
    for (int tap = 0; tap < 25; ++tap) {
        unsigned int p = pkv[tap];
        float x0 = (float)(p & 1u);
        float x1 = (float)((p >> 1) & 1u);
        const float4* wv0 = (const float4*)&wTg1[tap * 16];
        const float4* wv1 = (const float4*)&wTg1[(25 + tap) * 16];
        #pragma unroll
        for (int j = 0; j < 4; ++j) {
            float4 w = wv0[j];
            acc[j*4+0] = fmaf(w.x, x0, acc[j*4+0]);
            acc[j*4+1] = fmaf(w.y, x0, acc[j*4+1]);
            acc[j*4+2] = fmaf(w.z, x0, acc[j*4+2]);
            acc[j*4+3] = fmaf(w.w, x0, acc[j*4+3]);
        }
        #pragma unroll
        for (int j = 0; j < 4; ++j) {
            float4 w = wv1[j];
            acc[j*4+0] = fmaf(w.x, x1, acc[j*4+0]);
            acc[j*4+1] = fmaf(w.y, x1, acc[j*4+1]);
            acc[j*4+2] = fmaf(w.z, x1, acc[j*4+2]);
            acc[j*4+3] = fmaf(w.w, x1, acc[j*4+3]);
        }
    }
    #pragma unroll
    for (int oc = 0; oc < 16; ++oc) sb[t][oc*2 + pos] = acc[oc];
    __syncthreads();
    if (threadIdx.x < 32) lif_seq_lds(&sb[0][threadIdx.x], 33);
    __syncthreads();
    size_t obase = (((size_t)(b*16) * 32 + py) * 32 + px) * 128 + t;
    #pragma unroll
    for (int oc = 0; oc < 16; ++oc)
        s2[obase + (size_t)oc * 131072] = sb[t][oc*2 + pos];
}

// ---------------- L3: sum_pool(s2,2)*88 (delayed) + LIF ----------------
__global__ void pool2_lif_k(const float* __restrict__ s2, float* __restrict__ s3) {
    __shared__ float sb[TT][3];
    int t = threadIdx.x & 127, pos = threadIdx.x >> 7;
    int n = blockIdx.x * 2 + pos;
    int px = n & 15, py = (n >> 4) & 15, c = (n >> 8) & 15, b = n >> 12;
    float acc = 0.f;
    if (t > 0) {
        const float* ip = s2 + (size_t)(((b*16 + c)*32 + py*2)*32 + px*2) * 128 + (t - 1);
        acc = (ip[0] + ip[128] + ip[32*128] + ip[33*128]) * POOLW;
    }
    sb[t][pos] = acc;
    __syncthreads();
    if (threadIdx.x < 2) lif_seq_lds(&sb[0][threadIdx.x], 3);
    __syncthreads();
    s3[(size_t)n * TT + t] = sb[t][pos];
}

// ---------------- L4: conv2 3x3 SAME 16->32 (delayed, bit-packed input) + LIF -----
__global__ __launch_bounds__(256) void conv2_lif_k(const unsigned short* __restrict__ pk3,
                                                   const float* __restrict__ wTg2,
                                                   float* __restrict__ s4) {
    __shared__ float sb[TT][65];
    int id = blockIdx.x * 256 + threadIdx.x;
    int t = id & 127, pos = threadIdx.x >> 7;
    int n = id >> 7;
    int px = n & 15, py = (n >> 4) & 15, b = n >> 8;
    int tsrc = t > 0 ? t - 1 : 0;
    const unsigned short* pp = pk3 + (size_t)b * 32768 + tsrc;
    // all 9 tap loads upfront
    unsigned int pkv[9];
    #pragma unroll
    for (int ky = 0; ky < 3; ++ky) {
        int iy = py + ky - 1;
        #pragma unroll
        for (int kx = 0; kx < 3; ++kx) {
            int ix = px + kx - 1;
            bool valid = ((unsigned)iy < 16u) && ((unsigned)ix < 16u) && (t > 0);
            int iyc = valid ? iy : 0, ixc = valid ? ix : 0;
            unsigned int v = pp[(iyc*16 + ixc) * 128];
            pkv[ky*3 + kx] = valid ? v : 0u;
        }
    }
    float acc[32];
    #pragma unroll
    for (int k = 0; k < 32; ++k) acc[k] = 0.f;
    #pragma unroll
    for (int tap = 0; tap < 9; ++tap) {
        unsigned int p = pkv[tap];
        #pragma unroll
        for (int c = 0; c < 16; ++c) {
            float xc = (float)((p >> c) & 1u);
            const float4* wv = (const float4*)&wTg2[(c*9 + tap) * 32];
            #pragma unroll
            for (int j = 0; j < 8; ++j) {
                float4 w = wv[j];
                acc[j*4+0] = fmaf(w.x, xc, acc[j*4+0]);
                acc[j*4+1] = fmaf(w.y, xc, acc[j*4+1]);
                acc[j*4+2] = fmaf(w.z, xc, acc[j*4+2]);
                acc[j*4+3] = fmaf(w.w, xc, acc[j*4+3]);
            }
        }
    }
    #pragma unroll
    for (int oc = 0; oc < 32; ++oc) sb[t][oc*2 + pos] = acc[oc];
    __syncthreads();
    if (threadIdx.x < 64) lif_seq_lds(&sb[0][threadIdx.x], 65);
    __syncthreads();
    size_t obase = (((size_t)(b*32) * 16 + py) * 16 + px) * 128 + t;
    #pragma unroll
    for (int oc = 0; oc < 32; ++oc)
        s4[obase + (size_t)oc * 32768] = sb[t][oc*2 + pos];
}

// ---------------- L5: sum_pool(s4,2)*88 (delayed) + LIF ----------------
__global__ void pool3_lif_k(const float* __restrict__ s4, float* __restrict__ s5) {
    __shared__ float sb[TT][3];
    int t = threadIdx.x & 127, pos = threadIdx.x >> 7;
    int n = blockIdx.x * 2 + pos;
    int px = n & 7, py = (n >> 3) & 7, c = (n >> 6) & 31, b = n >> 11;
    float acc = 0.f;
    if (t > 0) {
        const float* ip = s4 + (size_t)(((b*32 + c)*16 + py*2)*16 + px*2) * 128 + (t - 1);
        acc = (ip[0] + ip[128] + ip[16*128] + ip[17*128]) * POOLW;
    }
    sb[t][pos] = acc;
    __syncthreads();
    if (threadIdx.x < 2) lif_seq_lds(&sb[0][threadIdx.x], 3);
    __syncthreads();
    s5[(size_t)n * TT + t] = sb[t][pos];
}

// ---------------- L6: fc1 tiled K-split GEMM ----------------
__global__ __launch_bounds__(256) void fc1_gemm_k(const float* __restrict__ s5,
                                                  const float* __restrict__ wf1,
                                                  float* __restrict__ part) {
    __shared__ float WT[64][68];
    __shared__ float ST[64][68];
    int bid = blockIdx.x;
    int kc = bid & 7;
    int ot = (bid >> 3) & 7;
    int tt = (bid >> 6) & 1;
    int b  = bid >> 7;
    int tid = threadIdx.x;
    int oo = tid >> 4;
    int to = tid & 15;

    const float* wbase = wf1 + (size_t)(ot*64) * 2048 + kc*256;
    const float* sbase = s5 + (size_t)b * 262144 + (size_t)(kc*256) * 128;

    float acc[4][4];
    #pragma unroll
    for (int i = 0; i < 4; ++i)
        #pragma unroll
        for (int j = 0; j < 4; ++j) acc[i][j] = 0.f;

    for (int ks = 0; ks < 4; ++ks) {
        __syncthreads();
        #pragma unroll
        for (int i = 0; i < 16; ++i) {
            int e = tid + 256*i;
            int o = e >> 6, f = e & 63;
            WT[f][o] = wbase[(size_t)o * 2048 + ks*64 + f];
        }
        #pragma unroll
        for (int i = 0; i < 16; ++i) {
            int e = tid + 256*i;
            int f = e >> 6, tl = e & 63;
            int tsrc = tt*64 + tl - 1;
            ST[f][tl] = (tsrc < 0) ? 0.f : sbase[(size_t)f * 128 + ks*64*128 + tsrc];
        }
        __syncthreads();
        #pragma unroll 4
        for (int k = 0; k < 64; ++k) {
            float4 a = *(const float4*)&WT[k][oo*4];
            float4 s = *(const float4*)&ST[k][to*4];
            acc[0][0] = fmaf(a.x, s.x, acc[0][0]);
            acc[0][1] = fmaf(a.x, s.y, acc[0][1]);
            acc[0][2] = fmaf(a.x, s.z, acc[0][2]);
            acc[0][3] = fmaf(a.x, s.w, acc[0][3]);
            acc[1][0] = fmaf(a.y, s.x, acc[1][0]);
            acc[1][1] = fmaf(a.y, s.y, acc[1][1]);
            acc[1][2] = fmaf(a.y, s.z, acc[1][2]);
            acc[1][3] = fmaf(a.y, s.w, acc[1][3]);
            acc[2][0] = fmaf(a.z, s.x, acc[2][0]);
            acc[2][1] = fmaf(a.z, s.y, acc[2][1]);
            acc[2][2] = fmaf(a.z, s.z, acc[2][2]);
            acc[2][3] = fmaf(a.z, s.w, acc[2][3]);
            acc[3][0] = fmaf(a.w, s.x, acc[3][0]);
            acc[3][1] = fmaf(a.w, s.y, acc[3][1]);
            acc[3][2] = fmaf(a.w, s.z, acc[3][2]);
            acc[3][3] = fmaf(a.w, s.w, acc[3][3]);
        }
    }
    float* pb = part + (size_t)kc * 524288 + (size_t)b * 65536
              + (size_t)(ot*64 + oo*4) * 128 + tt*64 + to*4;
    #pragma unroll
    for (int i = 0; i < 4; ++i)
        #pragma unroll
        for (int j = 0; j < 4; ++j)
            pb[(size_t)i * 128 + j] = acc[i][j];
}

// ---------------- L6b: sum 8 K-chunks (fixed order) + LIF -> s6 ----------------
__global__ void fc1_reduce_lif_k(const float* __restrict__ part, float* __restrict__ s6) {
    __shared__ float sb[TT][3];
    int t = threadIdx.x & 127, pos = threadIdx.x >> 7;
    int n = blockIdx.x * 2 + pos;
    float s = 0.f;
    #pragma unroll
    for (int kc = 0; kc < 8; ++kc)
        s += part[(size_t)kc * 524288 + (size_t)n * 128 + t];
    sb[t][pos] = s;
    __syncthreads();
    if (threadIdx.x < 2) lif_seq_lds(&sb[0][threadIdx.x], 3);
    __syncthreads();
    s6[(size_t)n * TT + t] = sb[t][pos];
}

// ---------------- L7: fc2 512->11 (delayed) + LIF + final shift -> out ----------
__global__ void fc2_lif_k(const float* __restrict__ s6, const float* __restrict__ wf2,
                          float* __restrict__ out) {
    __shared__ float sb[TT];
    int t = threadIdx.x;
    int o = blockIdx.x % 11, b = blockIdx.x / 11;
    float acc = 0.f;
    if (t > 0) {
        const float* sp = s6 + (size_t)b * 65536 + (t - 1);
        const float* wp = wf2 + o * 512;
        for (int f = 0; f < 512; f += 4) {
            float4 w = *(const float4*)&wp[f];
            acc = fmaf(w.x, sp[(size_t)f * 128], acc);
            acc = fmaf(w.y, sp[(size_t)(f+1) * 128], acc);
            acc = fmaf(w.z, sp[(size_t)(f+2) * 128], acc);
            acc = fmaf(w.w, sp[(size_t)(f+3) * 128], acc);
        }
    }
    sb[t] = acc;
    __syncthreads();
    if (t == 0) lif_seq_lds(sb, 1);
    __syncthreads();
    float* q = out + (size_t)(b*11 + o) * TT;
    if (t == 0) q[0] = 0.f;
    if (t < TT - 1) q[t + 1] = sb[t];
}

extern "C" void kernel_launch(void* const* d_in, const int* in_sizes, int n_in,
                              void* d_out, int out_size, void* d_ws, size_t ws_size,
                              hipStream_t stream) {
    const float* x   = (const float*)d_in[0];
    const float* w1  = (const float*)d_in[1];
    const float* w2  = (const float*)d_in[2];
    const float* wf1 = (const float*)d_in[3];
    const float* wf2 = (const float*)d_in[4];
    float* out = (float*)d_out;

    float* ws = (float*)d_ws;
    float* A    = ws;                        // 4,194,304 floats (s1/s3/s5)
    float* B    = ws + 4194304;              // 16,777,216 floats (s2; later s6)
    float* PART = B + 1048576;               // 4,194,304 floats
    float* D4   = ws + 4194304 + 16777216;   // 8,388,608 floats (s4)
    float* WT1  = D4 + 8388608;              // 800 floats
    float* WT2  = WT1 + 800;                 // 4608 floats
    unsigned char*  PK1 = (unsigned char*)(WT2 + 4608);   // 1,048,576 B
    unsigned short* PK3 = (unsigned short*)(PK1 + 1048576); // 262,144 x 2B

    // W transpose (oc contiguous) for the SGPR weight path
    wtrans_k<<<dim3(18), 256, 0, stream>>>(w1, w2, WT1, WT2);
    // L1: pool1+LIF   (A = s1)
    pool1_lif_k<<<dim3(8192), 256, 0, stream>>>(x, A);
    // pack s1 -> PK1
    pack1_k<<<dim3(4096), 256, 0, stream>>>(A, PK1);
    // L2: conv1+LIF   (B = s2)
    conv1_lif_k<<<dim3(4096), 256, 0, stream>>>(PK1, WT1, B);
    // L3: pool2+LIF   (A = s3)
    pool2_lif_k<<<dim3(16384), 256, 0, stream>>>(B, A);
    // pack s3 -> PK3
    pack2_k<<<dim3(1024), 256, 0, stream>>>(A, PK3);
    // L4: conv2+LIF   (D4 = s4)
    conv2_lif_k<<<dim3(1024), 256, 0, stream>>>(PK3, WT2, D4);
    // L5: pool3+LIF   (A = s5)
    pool3_lif_k<<<dim3(8192), 256, 0, stream>>>(D4, A);
    // L6: fc1 GEMM -> PART; reduce+LIF -> B (s6)
    fc1_gemm_k      <<<dim3(1024), 256, 0, stream>>>(A, wf1, PART);
    fc1_reduce_lif_k<<<dim3(2048), 256, 0, stream>>>(PART, B);
    // L7: fc2+LIF+shift -> d_out
    fc2_lif_k<<<dim3(88), 128, 0, stream>>>(B, wf2, out);
}